// Round 2
// baseline (881.666 us; speedup 1.0000x reference)
//
#include <hip/hip_runtime.h>

#define Bc 8
#define Nn 9216
#define Dd 256
#define Oo 512
#define EPSc 1e-5f

// workspace float offsets
#define OFF_MU1    0
#define OFF_RSTD1  73728
#define OFF_MU2    147456
#define OFF_RSTD2  221184
#define OFF_ROWINV 294912
#define OFF_COLSUM 368640
#define OFF_CTX    370688    // colsum+ctx zeroed together (contiguous)
#define OFF_M      894976
#define OFF_W2T    1419264
// total = 2,467,840 floats (~9.9 MB)

__global__ __launch_bounds__(256) void mg_k0_zero(float* __restrict__ p, int n4) {
    int i = blockIdx.x * 256 + threadIdx.x;
    if (i < n4) ((float4*)p)[i] = make_float4(0.f, 0.f, 0.f, 0.f);
}

// K1: one pass over x1,x2. Per row: LN stats for both; query row-sumexp; col-sumexp partials -> atomics.
__global__ __launch_bounds__(256) void mg_k1_stats(const float* __restrict__ x1, const float* __restrict__ x2,
                                                   const float* __restrict__ g1, const float* __restrict__ b1,
                                                   float* __restrict__ ws)
{
    float* mu1    = ws + OFF_MU1;
    float* rstd1  = ws + OFF_RSTD1;
    float* mu2    = ws + OFF_MU2;
    float* rstd2  = ws + OFF_RSTD2;
    float* rowinv = ws + OFF_ROWINV;
    float* colsum = ws + OFF_COLSUM;

    int t = threadIdx.x, lane = t & 63, w = t >> 6;
    int b = blockIdx.x / 144, rb = blockIdx.x % 144;
    int nbase = rb * 64;

    float4 g1v = ((const float4*)g1)[lane];
    float4 b1v = ((const float4*)b1)[lane];
    float cs0 = 0.f, cs1 = 0.f, cs2 = 0.f, cs3 = 0.f;
    __shared__ float csL[4][256];

    for (int i = 0; i < 16; ++i) {
        int n = nbase + i * 4 + w;
        int base = (b * Nn + n) * 64 + lane;
        float4 xa = ((const float4*)x1)[base];
        float4 xb = ((const float4*)x2)[base];
        float s1 = xa.x + xa.y + xa.z + xa.w;
        float q1 = xa.x*xa.x + xa.y*xa.y + xa.z*xa.z + xa.w*xa.w;
        float s2 = xb.x + xb.y + xb.z + xb.w;
        float q2 = xb.x*xb.x + xb.y*xb.y + xb.z*xb.z + xb.w*xb.w;
        #pragma unroll
        for (int m = 1; m < 64; m <<= 1) {
            s1 += __shfl_xor(s1, m); q1 += __shfl_xor(q1, m);
            s2 += __shfl_xor(s2, m); q2 += __shfl_xor(q2, m);
        }
        float m1 = s1 * (1.f / Dd), m2 = s2 * (1.f / Dd);
        float r1 = rsqrtf(q1 * (1.f / Dd) - m1 * m1 + EPSc);
        float r2 = rsqrtf(q2 * (1.f / Dd) - m2 * m2 + EPSc);
        int ni = b * Nn + n;
        if (lane == 0) { mu1[ni] = m1; rstd1[ni] = r1; mu2[ni] = m2; rstd2[ni] = r2; }
        // LN(x2) values are bounded -> exp without max-subtraction is safe in f32
        float e0 = __expf((xb.x - m2) * r2 * g1v.x + b1v.x);
        float e1 = __expf((xb.y - m2) * r2 * g1v.y + b1v.y);
        float e2 = __expf((xb.z - m2) * r2 * g1v.z + b1v.z);
        float e3 = __expf((xb.w - m2) * r2 * g1v.w + b1v.w);
        float rs = e0 + e1 + e2 + e3;
        #pragma unroll
        for (int m = 1; m < 64; m <<= 1) rs += __shfl_xor(rs, m);
        if (lane == 0) rowinv[ni] = 1.f / rs;
        cs0 += e0; cs1 += e1; cs2 += e2; cs3 += e3;
    }
    csL[w][lane * 4 + 0] = cs0;
    csL[w][lane * 4 + 1] = cs1;
    csL[w][lane * 4 + 2] = cs2;
    csL[w][lane * 4 + 3] = cs3;
    __syncthreads();
    float tot = csL[0][t] + csL[1][t] + csL[2][t] + csL[3][t];
    atomicAdd(&colsum[b * Dd + t], tot);
}

// K3: context_raw[b][d][e] = sum_n exp(n2[n][d]) * n1[n][e]  (split-K over N, atomic accumulate)
// grid: b(8) x ks(16) x db(4); block tile [64 d x 256 e], per-thread 4d x 16e
__global__ __launch_bounds__(256) void mg_k3_ctx(const float* __restrict__ x1, const float* __restrict__ x2,
                                                 const float* __restrict__ g1, const float* __restrict__ b1,
                                                 float* __restrict__ ws)
{
    __shared__ float x1t[32][256];
    __shared__ float at[32][64];
    __shared__ float g1s[256], b1s[256];
    const float* mu1   = ws + OFF_MU1;
    const float* rstd1 = ws + OFF_RSTD1;
    const float* mu2   = ws + OFF_MU2;
    const float* rstd2 = ws + OFF_RSTD2;
    float* ctx = ws + OFF_CTX;

    int t = threadIdx.x;
    int b = blockIdx.x >> 6, ks = (blockIdx.x >> 2) & 15, db = blockIdx.x & 3;
    int d0 = db * 64;
    g1s[t] = g1[t]; b1s[t] = b1[t];

    float acc[4][16];
    #pragma unroll
    for (int i = 0; i < 4; ++i)
        #pragma unroll
        for (int j = 0; j < 16; ++j) acc[i][j] = 0.f;

    int qd = t & 15;   // d = d0 + 4*qd
    int qe = t >> 4;   // e = 16*qe
    int nbase = ks * 576;

    for (int st = 0; st < 18; ++st) {
        int r0 = nbase + st * 32;
        __syncthreads();
        #pragma unroll
        for (int k = 0; k < 8; ++k) {
            int fi = t + k * 256;
            int row = fi >> 6, c4 = fi & 63;
            int ni = b * Nn + r0 + row;
            float4 xv = ((const float4*)x1)[ni * 64 + c4];
            float m = mu1[ni], r = rstd1[ni];
            float4 o;
            o.x = (xv.x - m) * r * g1s[c4 * 4 + 0] + b1s[c4 * 4 + 0];
            o.y = (xv.y - m) * r * g1s[c4 * 4 + 1] + b1s[c4 * 4 + 1];
            o.z = (xv.z - m) * r * g1s[c4 * 4 + 2] + b1s[c4 * 4 + 2];
            o.w = (xv.w - m) * r * g1s[c4 * 4 + 3] + b1s[c4 * 4 + 3];
            *(float4*)&x1t[row][c4 * 4] = o;
        }
        #pragma unroll
        for (int k = 0; k < 2; ++k) {
            int fi = t + k * 256;
            int row = fi >> 4, c4 = fi & 15;
            int ni = b * Nn + r0 + row;
            int d = d0 + c4 * 4;
            float4 xv = ((const float4*)x2)[ni * 64 + (d >> 2)];
            float m = mu2[ni], r = rstd2[ni];
            float4 o;
            o.x = __expf((xv.x - m) * r * g1s[d + 0] + b1s[d + 0]);
            o.y = __expf((xv.y - m) * r * g1s[d + 1] + b1s[d + 1]);
            o.z = __expf((xv.z - m) * r * g1s[d + 2] + b1s[d + 2]);
            o.w = __expf((xv.w - m) * r * g1s[d + 3] + b1s[d + 3]);
            *(float4*)&at[row][c4 * 4] = o;
        }
        __syncthreads();
        #pragma unroll 4
        for (int n = 0; n < 32; ++n) {
            float4 a  = *(const float4*)&at[n][qd * 4];
            float4 v0 = *(const float4*)&x1t[n][qe * 16 + 0];
            float4 v1 = *(const float4*)&x1t[n][qe * 16 + 4];
            float4 v2 = *(const float4*)&x1t[n][qe * 16 + 8];
            float4 v3 = *(const float4*)&x1t[n][qe * 16 + 12];
            float av[4] = {a.x, a.y, a.z, a.w};
            float ev[16] = {v0.x, v0.y, v0.z, v0.w, v1.x, v1.y, v1.z, v1.w,
                            v2.x, v2.y, v2.z, v2.w, v3.x, v3.y, v3.z, v3.w};
            #pragma unroll
            for (int i = 0; i < 4; ++i)
                #pragma unroll
                for (int j = 0; j < 16; ++j)
                    acc[i][j] = fmaf(av[i], ev[j], acc[i][j]);
        }
    }
    #pragma unroll
    for (int i = 0; i < 4; ++i) {
        int d = d0 + qd * 4 + i;
        float* rowp = ctx + (b * Dd + d) * Dd + qe * 16;
        #pragma unroll
        for (int j = 0; j < 16; ++j) atomicAdd(&rowp[j], acc[i][j]);
    }
}

// K5: per context row: scale by 1/colsum, bitonic sort (desc), 4 top-k thresholds,
// combined masked softmax M = sum_i a_i * softmax_masked_i.  grid = B*D rows.
__global__ __launch_bounds__(256) void mg_k5_mask(const float* __restrict__ a1p, const float* __restrict__ a2p,
                                                  const float* __restrict__ a3p, const float* __restrict__ a4p,
                                                  float* __restrict__ ws)
{
    const float* ctx    = ws + OFF_CTX;
    const float* colsum = ws + OFF_COLSUM;
    float* Mo = ws + OFF_M;
    int t = threadIdx.x;
    int b = blockIdx.x >> 8, d = blockIdx.x & 255;
    __shared__ float s[256];
    __shared__ float wred[4][4];

    float inv = 1.f / colsum[b * Dd + d];
    float c = ctx[(b * Dd + d) * Dd + t] * inv;
    s[t] = c;
    __syncthreads();
    // bitonic sort descending
    for (int k = 2; k <= 256; k <<= 1) {
        for (int j = k >> 1; j > 0; j >>= 1) {
            int ixj = t ^ j;
            if (ixj > t) {
                float A = s[t], Bv = s[ixj];
                bool desc = ((t & k) == 0);
                bool sw = desc ? (A < Bv) : (A > Bv);
                if (sw) { s[t] = Bv; s[ixj] = A; }
            }
            __syncthreads();
        }
    }
    float cmax = s[0];
    float t0 = s[127], t1 = s[169], t2 = s[191], t3 = s[203];  // k-1 for k = 128,170,192,204
    float e = __expf(c - cmax);
    float w0 = (c >= t0) ? e : 0.f;
    float w1 = (c >= t1) ? e : 0.f;
    float w2 = (c >= t2) ? e : 0.f;
    float w3 = (c >= t3) ? e : 0.f;
    float v0 = w0, v1 = w1, v2 = w2, v3 = w3;
    #pragma unroll
    for (int m = 1; m < 64; m <<= 1) {
        v0 += __shfl_xor(v0, m); v1 += __shfl_xor(v1, m);
        v2 += __shfl_xor(v2, m); v3 += __shfl_xor(v3, m);
    }
    int lane = t & 63, wv = t >> 6;
    if (lane == 0) { wred[wv][0] = v0; wred[wv][1] = v1; wred[wv][2] = v2; wred[wv][3] = v3; }
    __syncthreads();
    float S0 = wred[0][0] + wred[1][0] + wred[2][0] + wred[3][0];
    float S1 = wred[0][1] + wred[1][1] + wred[2][1] + wred[3][1];
    float S2 = wred[0][2] + wred[1][2] + wred[2][2] + wred[3][2];
    float S3 = wred[0][3] + wred[1][3] + wred[2][3] + wred[3][3];
    float Mv = a1p[0] * (w0 / S0) + a2p[0] * (w1 / S1) + a3p[0] * (w2 / S2) + a4p[0] * (w3 / S3);
    Mo[(b * Dd + d) * Dd + t] = Mv;
}

// K6: W2T[b][e][o] = sum_c Wr[o][c] * M[b][c][e].  grid: b(8) x ob(16,o-32) x eh(2,e-128)
__global__ __launch_bounds__(256) void mg_k6_w2(const float* __restrict__ Wr, float* __restrict__ ws)
{
    const float* Mo = ws + OFF_M;
    float* W2T = ws + OFF_W2T;
    __shared__ float Mt[32][128];
    __shared__ float WrT[32][36];
    int t = threadIdx.x;
    int b = blockIdx.x >> 5, ob = (blockIdx.x >> 1) & 15, eh = blockIdx.x & 1;
    int o0 = ob * 32, e0 = eh * 128;
    int ol4 = t & 7, el = t >> 3;   // o = o0+4*ol4+i, e = e0+4*el+j
    float acc[4][4];
    #pragma unroll
    for (int i = 0; i < 4; ++i)
        #pragma unroll
        for (int j = 0; j < 4; ++j) acc[i][j] = 0.f;

    for (int ch = 0; ch < 8; ++ch) {
        int c0 = ch * 32;
        __syncthreads();
        #pragma unroll
        for (int k = 0; k < 4; ++k) {
            int fi = t + k * 256;
            int row = fi >> 5, c4 = fi & 31;
            float4 mv = ((const float4*)Mo)[(b * Dd + c0 + row) * 64 + (e0 >> 2) + c4];
            *(float4*)&Mt[row][c4 * 4] = mv;
        }
        {
            int ol = t >> 3, c4 = t & 7;
            float4 wv = ((const float4*)Wr)[(o0 + ol) * 64 + (c0 >> 2) + c4];
            WrT[c4 * 4 + 0][ol] = wv.x;
            WrT[c4 * 4 + 1][ol] = wv.y;
            WrT[c4 * 4 + 2][ol] = wv.z;
            WrT[c4 * 4 + 3][ol] = wv.w;
        }
        __syncthreads();
        #pragma unroll
        for (int cc = 0; cc < 32; ++cc) {
            float4 w4 = *(const float4*)&WrT[cc][ol4 * 4];
            float4 m4 = *(const float4*)&Mt[cc][el * 4];
            float wv[4] = {w4.x, w4.y, w4.z, w4.w};
            float mv[4] = {m4.x, m4.y, m4.z, m4.w};
            #pragma unroll
            for (int i = 0; i < 4; ++i)
                #pragma unroll
                for (int j = 0; j < 4; ++j)
                    acc[i][j] = fmaf(wv[i], mv[j], acc[i][j]);
        }
    }
    #pragma unroll
    for (int j = 0; j < 4; ++j) {
        float4 v = make_float4(acc[0][j], acc[1][j], acc[2][j], acc[3][j]);
        *(float4*)&W2T[(b * Dd + e0 + el * 4 + j) * Oo + o0 + ol4 * 4] = v;
    }
}

// q LDS layout: f4-slot swizzle so reads are conflict-free b128 and writes spread 8 banks
#define QIDX4(c, n4) ((c) * 32 + ((((n4) ^ (((c) >> 2) & 7))) << 2))

// K7: rep[o][n] = sum_e W2T[e][o]*query[e][n] + br[o]; LN over o; store out[b][o][n]
// grid: b(8) x nt(288); tile 512o x 32n; thread: no=t&3 (8 n), oo=t>>2 (8 o)
__global__ __launch_bounds__(256, 2) void mg_k7_final(const float* __restrict__ x2,
        const float* __restrict__ g1, const float* __restrict__ b1,
        const float* __restrict__ br, const float* __restrict__ g2, const float* __restrict__ b2,
        const float* __restrict__ ws, float* __restrict__ out)
{
    __shared__ float qs[256 * 32];
    __shared__ float w2t[8][512];
    __shared__ float g1s[256], b1s[256];
    __shared__ float g2s[512], b2s[512], brs[512];
    __shared__ float stat[4][4][8][2];
    __shared__ float musig[32][2];
    const float* mu2    = ws + OFF_MU2;
    const float* rstd2  = ws + OFF_RSTD2;
    const float* rowinv = ws + OFF_ROWINV;
    const float* W2T    = ws + OFF_W2T;

    int t = threadIdx.x;
    int b = blockIdx.x / 288, nt = blockIdx.x % 288;
    int n0 = nt * 32;
    g1s[t] = g1[t]; b1s[t] = b1[t];
    g2s[t] = g2[t]; g2s[t + 256] = g2[t + 256];
    b2s[t] = b2[t]; b2s[t + 256] = b2[t + 256];
    brs[t] = br[t]; brs[t + 256] = br[t + 256];
    __syncthreads();

    // stage query tile [256 c][32 n] (swizzled)
    #pragma unroll
    for (int k = 0; k < 8; ++k) {
        int fi = t + k * 256;
        int row = fi >> 6, c4 = fi & 63;
        int ni = b * Nn + n0 + row;
        float4 xv = ((const float4*)x2)[ni * 64 + c4];
        float m = mu2[ni], r = rstd2[ni], ri = rowinv[ni];
        int c = c4 * 4;
        int r4 = row >> 2, r3 = row & 3;
        qs[QIDX4(c + 0, r4) + r3] = __expf((xv.x - m) * r * g1s[c + 0] + b1s[c + 0]) * ri;
        qs[QIDX4(c + 1, r4) + r3] = __expf((xv.y - m) * r * g1s[c + 1] + b1s[c + 1]) * ri;
        qs[QIDX4(c + 2, r4) + r3] = __expf((xv.z - m) * r * g1s[c + 2] + b1s[c + 2]) * ri;
        qs[QIDX4(c + 3, r4) + r3] = __expf((xv.w - m) * r * g1s[c + 3] + b1s[c + 3]) * ri;
    }
    __syncthreads();

    int no = t & 3, oo = t >> 2;
    float acc[8][8];
    #pragma unroll
    for (int i = 0; i < 8; ++i)
        #pragma unroll
        for (int j = 0; j < 8; ++j) acc[i][j] = 0.f;

    for (int ch = 0; ch < 32; ++ch) {
        int c0 = ch * 8;
        __syncthreads();
        #pragma unroll
        for (int k = 0; k < 4; ++k) {
            int fi = t + k * 256;
            int row = fi >> 7, o4 = fi & 127;
            *(float4*)&w2t[row][o4 * 4] = ((const float4*)W2T)[(b * Dd + c0 + row) * 128 + o4];
        }
        __syncthreads();
        #pragma unroll
        for (int cc = 0; cc < 8; ++cc) {
            int c = c0 + cc;
            int K = (c >> 2) & 7;
            float4 qa = *(const float4*)&qs[c * 32 + (((no << 1) ^ K) << 2)];
            float4 qb = *(const float4*)&qs[c * 32 + ((((no << 1) | 1) ^ K) << 2)];
            float4 wa = *(const float4*)&w2t[cc][oo * 8];
            float4 wb = *(const float4*)&w2t[cc][oo * 8 + 4];
            float wv[8] = {wa.x, wa.y, wa.z, wa.w, wb.x, wb.y, wb.z, wb.w};
            float qv[8] = {qa.x, qa.y, qa.z, qa.w, qb.x, qb.y, qb.z, qb.w};
            #pragma unroll
            for (int i = 0; i < 8; ++i)
                #pragma unroll
                for (int j = 0; j < 8; ++j)
                    acc[i][j] = fmaf(wv[i], qv[j], acc[i][j]);
        }
    }

    // epilogue: +br, LN over 512 channels per n-column, transposed store
    float ps[8], pq[8];
    #pragma unroll
    for (int j = 0; j < 8; ++j) { ps[j] = 0.f; pq[j] = 0.f; }
    #pragma unroll
    for (int i = 0; i < 8; ++i) {
        float bb = brs[oo * 8 + i];
        #pragma unroll
        for (int j = 0; j < 8; ++j) {
            float v = acc[i][j] + bb;
            acc[i][j] = v;
            ps[j] += v;
            pq[j] += v * v;
        }
    }
    #pragma unroll
    for (int m = 4; m < 64; m <<= 1) {
        #pragma unroll
        for (int j = 0; j < 8; ++j) { ps[j] += __shfl_xor(ps[j], m); pq[j] += __shfl_xor(pq[j], m); }
    }
    int lane = t & 63, wv_ = t >> 6;
    if (lane < 4) {
        #pragma unroll
        for (int j = 0; j < 8; ++j) { stat[wv_][lane][j][0] = ps[j]; stat[wv_][lane][j][1] = pq[j]; }
    }
    __syncthreads();
    if (t < 32) {
        int no_ = t >> 3, j_ = t & 7;
        float S = 0.f, Q = 0.f;
        #pragma unroll
        for (int w2 = 0; w2 < 4; ++w2) { S += stat[w2][no_][j_][0]; Q += stat[w2][no_][j_][1]; }
        float mu = S * (1.f / Oo);
        float var = Q * (1.f / Oo) - mu * mu;
        musig[t][0] = mu;
        musig[t][1] = rsqrtf(var + EPSc);
    }
    __syncthreads();
    #pragma unroll
    for (int i = 0; i < 8; ++i) {
        int o = oo * 8 + i;
        float g = g2s[o], bb2 = b2s[o];
        float vout[8];
        #pragma unroll
        for (int j = 0; j < 8; ++j) {
            int nl = no * 8 + j;
            vout[j] = (acc[i][j] - musig[nl][0]) * musig[nl][1] * g + bb2;
        }
        float4 A = make_float4(vout[0], vout[1], vout[2], vout[3]);
        float4 Bv = make_float4(vout[4], vout[5], vout[6], vout[7]);
        int obase = (b * Oo + o) * Nn + n0 + no * 8;
        *(float4*)&out[obase] = A;
        *(float4*)&out[obase + 4] = Bv;
    }
}

extern "C" void kernel_launch(void* const* d_in, const int* in_sizes, int n_in,
                              void* d_out, int out_size, void* d_ws, size_t ws_size,
                              hipStream_t stream)
{
    (void)in_sizes; (void)n_in; (void)out_size; (void)ws_size;
    const float* x1 = (const float*)d_in[0];
    const float* x2 = (const float*)d_in[1];
    const float* g1 = (const float*)d_in[2];
    const float* b1 = (const float*)d_in[3];
    const float* Wr = (const float*)d_in[4];
    const float* br = (const float*)d_in[5];
    const float* g2 = (const float*)d_in[6];
    const float* b2 = (const float*)d_in[7];
    const float* a1 = (const float*)d_in[8];
    const float* a2 = (const float*)d_in[9];
    const float* a3 = (const float*)d_in[10];
    const float* a4 = (const float*)d_in[11];
    float* ws = (float*)d_ws;
    float* out = (float*)d_out;

    hipLaunchKernelGGL(mg_k0_zero, dim3(514), dim3(256), 0, stream, ws + OFF_COLSUM, 131584);
    hipLaunchKernelGGL(mg_k1_stats, dim3(1152), dim3(256), 0, stream, x1, x2, g1, b1, ws);
    hipLaunchKernelGGL(mg_k3_ctx, dim3(512), dim3(256), 0, stream, x1, x2, g1, b1, ws);
    hipLaunchKernelGGL(mg_k5_mask, dim3(2048), dim3(256), 0, stream, a1, a2, a3, a4, ws);
    hipLaunchKernelGGL(mg_k6_w2, dim3(256), dim3(256), 0, stream, Wr, ws);
    hipLaunchKernelGGL(mg_k7_final, dim3(2304), dim3(256), 0, stream, x2, g1, b1, br, g2, b2, ws, out);
}

// Round 3
// 476.268 us; speedup vs baseline: 1.8512x; 1.8512x over previous
//
#include <hip/hip_runtime.h>

#define Bc 8
#define Nn 9216
#define Dd 256
#define Oo 512
#define EPSc 1e-5f

// workspace float offsets
#define OFF_MU1    0
#define OFF_RSTD1  73728
#define OFF_MU2    147456
#define OFF_RSTD2  221184
#define OFF_ROWINV 294912
#define OFF_COLSUM 368640
#define OFF_M      894976
#define OFF_W2T    1419264
#define OFF_CTXP   2467840   // nks * 524288 floats of ctx partials (adaptive)

__global__ __launch_bounds__(256) void mg_k0_zero(float* __restrict__ p, int n4) {
    int i = blockIdx.x * 256 + threadIdx.x;
    if (i < n4) ((float4*)p)[i] = make_float4(0.f, 0.f, 0.f, 0.f);
}

// K1: one pass over x1,x2. Per row: LN stats for both; query row-sumexp; col-sumexp partials -> atomics.
__global__ __launch_bounds__(256) void mg_k1_stats(const float* __restrict__ x1, const float* __restrict__ x2,
                                                   const float* __restrict__ g1, const float* __restrict__ b1,
                                                   float* __restrict__ ws)
{
    float* mu1    = ws + OFF_MU1;
    float* rstd1  = ws + OFF_RSTD1;
    float* mu2    = ws + OFF_MU2;
    float* rstd2  = ws + OFF_RSTD2;
    float* rowinv = ws + OFF_ROWINV;
    float* colsum = ws + OFF_COLSUM;

    int t = threadIdx.x, lane = t & 63, w = t >> 6;
    int b = blockIdx.x / 144, rb = blockIdx.x % 144;
    int nbase = rb * 64;

    float4 g1v = ((const float4*)g1)[lane];
    float4 b1v = ((const float4*)b1)[lane];
    float cs0 = 0.f, cs1 = 0.f, cs2 = 0.f, cs3 = 0.f;
    __shared__ float csL[4][256];

    for (int i = 0; i < 16; ++i) {
        int n = nbase + i * 4 + w;
        int base = (b * Nn + n) * 64 + lane;
        float4 xa = ((const float4*)x1)[base];
        float4 xb = ((const float4*)x2)[base];
        float s1 = xa.x + xa.y + xa.z + xa.w;
        float q1 = xa.x*xa.x + xa.y*xa.y + xa.z*xa.z + xa.w*xa.w;
        float s2 = xb.x + xb.y + xb.z + xb.w;
        float q2 = xb.x*xb.x + xb.y*xb.y + xb.z*xb.z + xb.w*xb.w;
        #pragma unroll
        for (int m = 1; m < 64; m <<= 1) {
            s1 += __shfl_xor(s1, m); q1 += __shfl_xor(q1, m);
            s2 += __shfl_xor(s2, m); q2 += __shfl_xor(q2, m);
        }
        float m1 = s1 * (1.f / Dd), m2 = s2 * (1.f / Dd);
        float r1 = rsqrtf(q1 * (1.f / Dd) - m1 * m1 + EPSc);
        float r2 = rsqrtf(q2 * (1.f / Dd) - m2 * m2 + EPSc);
        int ni = b * Nn + n;
        if (lane == 0) { mu1[ni] = m1; rstd1[ni] = r1; mu2[ni] = m2; rstd2[ni] = r2; }
        // LN(x2) values are bounded -> exp without max-subtraction is safe in f32
        float e0 = __expf((xb.x - m2) * r2 * g1v.x + b1v.x);
        float e1 = __expf((xb.y - m2) * r2 * g1v.y + b1v.y);
        float e2 = __expf((xb.z - m2) * r2 * g1v.z + b1v.z);
        float e3 = __expf((xb.w - m2) * r2 * g1v.w + b1v.w);
        float rs = e0 + e1 + e2 + e3;
        #pragma unroll
        for (int m = 1; m < 64; m <<= 1) rs += __shfl_xor(rs, m);
        if (lane == 0) rowinv[ni] = 1.f / rs;
        cs0 += e0; cs1 += e1; cs2 += e2; cs3 += e3;
    }
    csL[w][lane * 4 + 0] = cs0;
    csL[w][lane * 4 + 1] = cs1;
    csL[w][lane * 4 + 2] = cs2;
    csL[w][lane * 4 + 3] = cs3;
    __syncthreads();
    float tot = csL[0][t] + csL[1][t] + csL[2][t] + csL[3][t];
    atomicAdd(&colsum[b * Dd + t], tot);
}

// K3 v3: ctx_partial[p][b][d][e] = sum_{n in slice p} exp(n2[n][d]) * n1[n][e]
// grid: b(8) x ks(nks) x 8 tiles (4 db x 2 eb); block tile 64d x 128e; thread 4d x 8e.
// No atomics: each ks-slice writes its own partial buffer; K5 reduces.
__global__ __launch_bounds__(256, 4) void mg_k3_ctx(const float* __restrict__ x1, const float* __restrict__ x2,
                                                    const float* __restrict__ g1, const float* __restrict__ b1,
                                                    float* __restrict__ ws, int nks)
{
    __shared__ float vL[32 * 128];   // n1 tile [32n][128e], float4-deinterleaved slots
    __shared__ float aL[32 * 64];    // exp(n2) tile [32n][64d]
    __shared__ float g1s[256], b1s[256];
    const float* mu1   = ws + OFF_MU1;
    const float* rstd1 = ws + OFF_RSTD1;
    const float* mu2   = ws + OFF_MU2;
    const float* rstd2 = ws + OFF_RSTD2;
    float* ctxp = ws + OFF_CTXP;

    int t = threadIdx.x;
    int bid = blockIdx.x;
    int tile = bid & 7;
    int db = tile >> 1, eb = tile & 1;
    int ks_i = (bid >> 3) % nks;
    int b = bid / (8 * nks);
    int d0 = db * 64, e0 = eb * 128;
    int krange = Nn / nks;
    int nst = krange >> 5;
    int n_base = ks_i * krange;

    g1s[t] = g1[t]; b1s[t] = b1[t];

    float4* vL4 = (float4*)vL;
    float4* aL4 = (float4*)aL;

    int tx = t & 15, ty = t >> 4;
    int vrow = t >> 5, vq = t & 31;
    int arow = t >> 4, aq = t & 15;
    int vdst = ((vq & 1) << 4) | (vq >> 1);   // de-interleave: even q -> 0..15, odd -> 16..31

    float acc[4][8];
    #pragma unroll
    for (int i = 0; i < 4; ++i)
        #pragma unroll
        for (int j = 0; j < 8; ++j) acc[i][j] = 0.f;

    for (int st = 0; st < nst; ++st) {
        int r0 = n_base + st * 32;
        __syncthreads();
        // stage n1 tile [32][128] (4 float4 per thread)
        #pragma unroll
        for (int k = 0; k < 4; ++k) {
            int row = vrow + k * 8;
            int ni = b * Nn + r0 + row;
            float4 xv = ((const float4*)x1)[(size_t)ni * 64 + (e0 >> 2) + vq];
            float m = mu1[ni], r = rstd1[ni];
            int c = e0 + vq * 4;
            float4 o;
            o.x = (xv.x - m) * r * g1s[c + 0] + b1s[c + 0];
            o.y = (xv.y - m) * r * g1s[c + 1] + b1s[c + 1];
            o.z = (xv.z - m) * r * g1s[c + 2] + b1s[c + 2];
            o.w = (xv.w - m) * r * g1s[c + 3] + b1s[c + 3];
            vL4[row * 32 + vdst] = o;
        }
        // stage exp(n2) tile [32][64] (2 float4 per thread)
        #pragma unroll
        for (int k = 0; k < 2; ++k) {
            int row = arow + k * 16;
            int ni = b * Nn + r0 + row;
            float4 xv = ((const float4*)x2)[(size_t)ni * 64 + (d0 >> 2) + aq];
            float m = mu2[ni], r = rstd2[ni];
            int c = d0 + aq * 4;
            float4 o;
            o.x = __expf((xv.x - m) * r * g1s[c + 0] + b1s[c + 0]);
            o.y = __expf((xv.y - m) * r * g1s[c + 1] + b1s[c + 1]);
            o.z = __expf((xv.z - m) * r * g1s[c + 2] + b1s[c + 2]);
            o.w = __expf((xv.w - m) * r * g1s[c + 3] + b1s[c + 3]);
            aL4[row * 16 + aq] = o;
        }
        __syncthreads();
        #pragma unroll 4
        for (int n = 0; n < 32; ++n) {
            float4 av = aL4[n * 16 + ty];           // d = d0 + ty*4 .. +3 (broadcast, conflict-free)
            float4 va = vL4[n * 32 + tx];           // e = e0 + tx*8 .. +3 (2-way, free)
            float4 vb = vL4[n * 32 + 16 + tx];      // e = e0 + tx*8+4 .. +7
            float A[4] = {av.x, av.y, av.z, av.w};
            float V[8] = {va.x, va.y, va.z, va.w, vb.x, vb.y, vb.z, vb.w};
            #pragma unroll
            for (int i = 0; i < 4; ++i)
                #pragma unroll
                for (int j = 0; j < 8; ++j)
                    acc[i][j] = fmaf(A[i], V[j], acc[i][j]);
        }
    }
    size_t obase = ((size_t)ks_i * Bc + b) * (Dd * Dd);
    #pragma unroll
    for (int i = 0; i < 4; ++i) {
        int d = d0 + ty * 4 + i;
        float* rp = ctxp + obase + (size_t)d * Dd + e0 + tx * 8;
        *(float4*)rp       = make_float4(acc[i][0], acc[i][1], acc[i][2], acc[i][3]);
        *(float4*)(rp + 4) = make_float4(acc[i][4], acc[i][5], acc[i][6], acc[i][7]);
    }
}

// K5: reduce ctx partials, scale by 1/colsum, bitonic sort (desc), 4 top-k thresholds,
// combined masked softmax M = sum_i a_i * softmax_masked_i.  grid = B*D rows.
__global__ __launch_bounds__(256) void mg_k5_mask(const float* __restrict__ a1p, const float* __restrict__ a2p,
                                                  const float* __restrict__ a3p, const float* __restrict__ a4p,
                                                  float* __restrict__ ws, int nks)
{
    const float* ctxp   = ws + OFF_CTXP;
    const float* colsum = ws + OFF_COLSUM;
    float* Mo = ws + OFF_M;
    int t = threadIdx.x;
    int b = blockIdx.x >> 8, d = blockIdx.x & 255;
    __shared__ float s[256];
    __shared__ float wred[4][4];

    float c = 0.f;
    for (int p = 0; p < nks; ++p)
        c += ctxp[((size_t)p * Bc + b) * (Dd * Dd) + (size_t)d * Dd + t];
    float inv = 1.f / colsum[b * Dd + d];
    c *= inv;
    s[t] = c;
    __syncthreads();
    // bitonic sort descending
    for (int k = 2; k <= 256; k <<= 1) {
        for (int j = k >> 1; j > 0; j >>= 1) {
            int ixj = t ^ j;
            if (ixj > t) {
                float A = s[t], Bv = s[ixj];
                bool desc = ((t & k) == 0);
                bool sw = desc ? (A < Bv) : (A > Bv);
                if (sw) { s[t] = Bv; s[ixj] = A; }
            }
            __syncthreads();
        }
    }
    float cmax = s[0];
    float t0 = s[127], t1 = s[169], t2 = s[191], t3 = s[203];  // k-1 for k = 128,170,192,204
    float e = __expf(c - cmax);
    float w0 = (c >= t0) ? e : 0.f;
    float w1 = (c >= t1) ? e : 0.f;
    float w2 = (c >= t2) ? e : 0.f;
    float w3 = (c >= t3) ? e : 0.f;
    float v0 = w0, v1 = w1, v2 = w2, v3 = w3;
    #pragma unroll
    for (int m = 1; m < 64; m <<= 1) {
        v0 += __shfl_xor(v0, m); v1 += __shfl_xor(v1, m);
        v2 += __shfl_xor(v2, m); v3 += __shfl_xor(v3, m);
    }
    int lane = t & 63, wv = t >> 6;
    if (lane == 0) { wred[wv][0] = v0; wred[wv][1] = v1; wred[wv][2] = v2; wred[wv][3] = v3; }
    __syncthreads();
    float S0 = wred[0][0] + wred[1][0] + wred[2][0] + wred[3][0];
    float S1 = wred[0][1] + wred[1][1] + wred[2][1] + wred[3][1];
    float S2 = wred[0][2] + wred[1][2] + wred[2][2] + wred[3][2];
    float S3 = wred[0][3] + wred[1][3] + wred[2][3] + wred[3][3];
    float Mv = a1p[0] * (w0 / S0) + a2p[0] * (w1 / S1) + a3p[0] * (w2 / S2) + a4p[0] * (w3 / S3);
    Mo[(b * Dd + d) * Dd + t] = Mv;
}

// K6: W2T[b][e][o] = sum_c Wr[o][c] * M[b][c][e].  grid: b(8) x ob(16,o-32) x eh(2,e-128)
__global__ __launch_bounds__(256) void mg_k6_w2(const float* __restrict__ Wr, float* __restrict__ ws)
{
    const float* Mo = ws + OFF_M;
    float* W2T = ws + OFF_W2T;
    __shared__ float Mt[32][128];
    __shared__ float WrT[32][36];
    int t = threadIdx.x;
    int b = blockIdx.x >> 5, ob = (blockIdx.x >> 1) & 15, eh = blockIdx.x & 1;
    int o0 = ob * 32, e0 = eh * 128;
    int ol4 = t & 7, el = t >> 3;   // o = o0+4*ol4+i, e = e0+4*el+j
    float acc[4][4];
    #pragma unroll
    for (int i = 0; i < 4; ++i)
        #pragma unroll
        for (int j = 0; j < 4; ++j) acc[i][j] = 0.f;

    for (int ch = 0; ch < 8; ++ch) {
        int c0 = ch * 32;
        __syncthreads();
        #pragma unroll
        for (int k = 0; k < 4; ++k) {
            int fi = t + k * 256;
            int row = fi >> 5, c4 = fi & 31;
            float4 mv = ((const float4*)Mo)[(b * Dd + c0 + row) * 64 + (e0 >> 2) + c4];
            *(float4*)&Mt[row][c4 * 4] = mv;
        }
        {
            int ol = t >> 3, c4 = t & 7;
            float4 wv = ((const float4*)Wr)[(o0 + ol) * 64 + (c0 >> 2) + c4];
            WrT[c4 * 4 + 0][ol] = wv.x;
            WrT[c4 * 4 + 1][ol] = wv.y;
            WrT[c4 * 4 + 2][ol] = wv.z;
            WrT[c4 * 4 + 3][ol] = wv.w;
        }
        __syncthreads();
        #pragma unroll
        for (int cc = 0; cc < 32; ++cc) {
            float4 w4 = *(const float4*)&WrT[cc][ol4 * 4];
            float4 m4 = *(const float4*)&Mt[cc][el * 4];
            float wv[4] = {w4.x, w4.y, w4.z, w4.w};
            float mv[4] = {m4.x, m4.y, m4.z, m4.w};
            #pragma unroll
            for (int i = 0; i < 4; ++i)
                #pragma unroll
                for (int j = 0; j < 4; ++j)
                    acc[i][j] = fmaf(wv[i], mv[j], acc[i][j]);
        }
    }
    #pragma unroll
    for (int j = 0; j < 4; ++j) {
        float4 v = make_float4(acc[0][j], acc[1][j], acc[2][j], acc[3][j]);
        *(float4*)&W2T[(b * Dd + e0 + el * 4 + j) * Oo + o0 + ol4 * 4] = v;
    }
}

// q LDS layout: f4-slot swizzle so reads are conflict-free b128 and writes spread 8 banks
#define QIDX4(c, n4) ((c) * 32 + ((((n4) ^ (((c) >> 2) & 7))) << 2))

// K7: rep[o][n] = sum_e W2T[e][o]*query[e][n] + br[o]; LN over o; store out[b][o][n]
// grid: b(8) x nt(288); tile 512o x 32n; thread: no=t&3 (8 n), oo=t>>2 (8 o)
__global__ __launch_bounds__(256, 2) void mg_k7_final(const float* __restrict__ x2,
        const float* __restrict__ g1, const float* __restrict__ b1,
        const float* __restrict__ br, const float* __restrict__ g2, const float* __restrict__ b2,
        const float* __restrict__ ws, float* __restrict__ out)
{
    __shared__ float qs[256 * 32];
    __shared__ float w2t[8][512];
    __shared__ float g1s[256], b1s[256];
    __shared__ float g2s[512], b2s[512], brs[512];
    __shared__ float stat[4][4][8][2];
    __shared__ float musig[32][2];
    const float* mu2    = ws + OFF_MU2;
    const float* rstd2  = ws + OFF_RSTD2;
    const float* rowinv = ws + OFF_ROWINV;
    const float* W2T    = ws + OFF_W2T;

    int t = threadIdx.x;
    int b = blockIdx.x / 288, nt = blockIdx.x % 288;
    int n0 = nt * 32;
    g1s[t] = g1[t]; b1s[t] = b1[t];
    g2s[t] = g2[t]; g2s[t + 256] = g2[t + 256];
    b2s[t] = b2[t]; b2s[t + 256] = b2[t + 256];
    brs[t] = br[t]; brs[t + 256] = br[t + 256];
    __syncthreads();

    // stage query tile [256 c][32 n] (swizzled)
    #pragma unroll
    for (int k = 0; k < 8; ++k) {
        int fi = t + k * 256;
        int row = fi >> 6, c4 = fi & 63;
        int ni = b * Nn + n0 + row;
        float4 xv = ((const float4*)x2)[ni * 64 + c4];
        float m = mu2[ni], r = rstd2[ni], ri = rowinv[ni];
        int c = c4 * 4;
        int r4 = row >> 2, r3 = row & 3;
        qs[QIDX4(c + 0, r4) + r3] = __expf((xv.x - m) * r * g1s[c + 0] + b1s[c + 0]) * ri;
        qs[QIDX4(c + 1, r4) + r3] = __expf((xv.y - m) * r * g1s[c + 1] + b1s[c + 1]) * ri;
        qs[QIDX4(c + 2, r4) + r3] = __expf((xv.z - m) * r * g1s[c + 2] + b1s[c + 2]) * ri;
        qs[QIDX4(c + 3, r4) + r3] = __expf((xv.w - m) * r * g1s[c + 3] + b1s[c + 3]) * ri;
    }
    __syncthreads();

    int no = t & 3, oo = t >> 2;
    float acc[8][8];
    #pragma unroll
    for (int i = 0; i < 8; ++i)
        #pragma unroll
        for (int j = 0; j < 8; ++j) acc[i][j] = 0.f;

    for (int ch = 0; ch < 32; ++ch) {
        int c0 = ch * 8;
        __syncthreads();
        #pragma unroll
        for (int k = 0; k < 4; ++k) {
            int fi = t + k * 256;
            int row = fi >> 7, o4 = fi & 127;
            *(float4*)&w2t[row][o4 * 4] = ((const float4*)W2T)[(b * Dd + c0 + row) * 128 + o4];
        }
        __syncthreads();
        #pragma unroll
        for (int cc = 0; cc < 8; ++cc) {
            int c = c0 + cc;
            int K = (c >> 2) & 7;
            float4 qa = *(const float4*)&qs[c * 32 + (((no << 1) ^ K) << 2)];
            float4 qb = *(const float4*)&qs[c * 32 + ((((no << 1) | 1) ^ K) << 2)];
            float4 wa = *(const float4*)&w2t[cc][oo * 8];
            float4 wb = *(const float4*)&w2t[cc][oo * 8 + 4];
            float wv[8] = {wa.x, wa.y, wa.z, wa.w, wb.x, wb.y, wb.z, wb.w};
            float qv[8] = {qa.x, qa.y, qa.z, qa.w, qb.x, qb.y, qb.z, qb.w};
            #pragma unroll
            for (int i = 0; i < 8; ++i)
                #pragma unroll
                for (int j = 0; j < 8; ++j)
                    acc[i][j] = fmaf(wv[i], qv[j], acc[i][j]);
        }
    }

    // epilogue: +br, LN over 512 channels per n-column, transposed store
    float ps[8], pq[8];
    #pragma unroll
    for (int j = 0; j < 8; ++j) { ps[j] = 0.f; pq[j] = 0.f; }
    #pragma unroll
    for (int i = 0; i < 8; ++i) {
        float bb = brs[oo * 8 + i];
        #pragma unroll
        for (int j = 0; j < 8; ++j) {
            float v = acc[i][j] + bb;
            acc[i][j] = v;
            ps[j] += v;
            pq[j] += v * v;
        }
    }
    #pragma unroll
    for (int m = 4; m < 64; m <<= 1) {
        #pragma unroll
        for (int j = 0; j < 8; ++j) { ps[j] += __shfl_xor(ps[j], m); pq[j] += __shfl_xor(pq[j], m); }
    }
    int lane = t & 63, wv_ = t >> 6;
    if (lane < 4) {
        #pragma unroll
        for (int j = 0; j < 8; ++j) { stat[wv_][lane][j][0] = ps[j]; stat[wv_][lane][j][1] = pq[j]; }
    }
    __syncthreads();
    if (t < 32) {
        int no_ = t >> 3, j_ = t & 7;
        float S = 0.f, Q = 0.f;
        #pragma unroll
        for (int w2 = 0; w2 < 4; ++w2) { S += stat[w2][no_][j_][0]; Q += stat[w2][no_][j_][1]; }
        float mu = S * (1.f / Oo);
        float var = Q * (1.f / Oo) - mu * mu;
        musig[t][0] = mu;
        musig[t][1] = rsqrtf(var + EPSc);
    }
    __syncthreads();
    #pragma unroll
    for (int i = 0; i < 8; ++i) {
        int o = oo * 8 + i;
        float g = g2s[o], bb2 = b2s[o];
        float vout[8];
        #pragma unroll
        for (int j = 0; j < 8; ++j) {
            int nl = no * 8 + j;
            vout[j] = (acc[i][j] - musig[nl][0]) * musig[nl][1] * g + bb2;
        }
        float4 A = make_float4(vout[0], vout[1], vout[2], vout[3]);
        float4 Bv = make_float4(vout[4], vout[5], vout[6], vout[7]);
        int obase = (b * Oo + o) * Nn + n0 + no * 8;
        *(float4*)&out[obase] = A;
        *(float4*)&out[obase + 4] = Bv;
    }
}

extern "C" void kernel_launch(void* const* d_in, const int* in_sizes, int n_in,
                              void* d_out, int out_size, void* d_ws, size_t ws_size,
                              hipStream_t stream)
{
    (void)in_sizes; (void)n_in; (void)out_size;
    const float* x1 = (const float*)d_in[0];
    const float* x2 = (const float*)d_in[1];
    const float* g1 = (const float*)d_in[2];
    const float* b1 = (const float*)d_in[3];
    const float* Wr = (const float*)d_in[4];
    const float* br = (const float*)d_in[5];
    const float* g2 = (const float*)d_in[6];
    const float* b2 = (const float*)d_in[7];
    const float* a1 = (const float*)d_in[8];
    const float* a2 = (const float*)d_in[9];
    const float* a3 = (const float*)d_in[10];
    const float* a4 = (const float*)d_in[11];
    float* ws = (float*)d_ws;
    float* out = (float*)d_out;

    // adaptive split-K count: partials must fit in workspace
    int nks = 16;
    while (nks > 1 && (2467840ull + (size_t)nks * 524288ull) * 4ull > ws_size) nks >>= 1;

    hipLaunchKernelGGL(mg_k0_zero, dim3(2), dim3(256), 0, stream, ws + OFF_COLSUM, 512);
    hipLaunchKernelGGL(mg_k1_stats, dim3(1152), dim3(256), 0, stream, x1, x2, g1, b1, ws);
    hipLaunchKernelGGL(mg_k3_ctx, dim3(Bc * nks * 8), dim3(256), 0, stream, x1, x2, g1, b1, ws, nks);
    hipLaunchKernelGGL(mg_k5_mask, dim3(2048), dim3(256), 0, stream, a1, a2, a3, a4, ws, nks);
    hipLaunchKernelGGL(mg_k6_w2, dim3(256), dim3(256), 0, stream, Wr, ws);
    hipLaunchKernelGGL(mg_k7_final, dim3(2304), dim3(256), 0, stream, x2, g1, b1, br, g2, b2, ws, out);
}

// Round 4
// 318.997 us; speedup vs baseline: 2.7639x; 1.4930x over previous
//
#include <hip/hip_runtime.h>
#include <hip/hip_bf16.h>

#define Bc 8
#define Nn 9216
#define Dd 256
#define Oo 512
#define EPSc 1e-5f

// workspace float offsets
#define OFF_MU1    0
#define OFF_RSTD1  73728
#define OFF_MU2    147456
#define OFF_RSTD2  221184
#define OFF_ROWINV 294912
#define OFF_COLSUM 368640
#define OFF_M      894976
#define OFF_W2T    1419264   // W2 bf16 [b][o][e] = 2 MB (524288 float slots)
#define OFF_CTXP   2467840   // nks * 524288 floats of ctx partials (adaptive)

typedef __attribute__((ext_vector_type(4))) float f32x4;
typedef __attribute__((ext_vector_type(8))) short short8;
typedef __attribute__((ext_vector_type(8))) unsigned short ushort8;

static __device__ __forceinline__ unsigned short f2bf(float f) {
    __hip_bfloat16 h = __float2bfloat16(f);
    union { __hip_bfloat16 hh; unsigned short uu; } cv; cv.hh = h;
    return cv.uu;
}

__global__ __launch_bounds__(256) void mg_k0_zero(float* __restrict__ p, int n4) {
    int i = blockIdx.x * 256 + threadIdx.x;
    if (i < n4) ((float4*)p)[i] = make_float4(0.f, 0.f, 0.f, 0.f);
}

// K1: one pass over x1,x2. Per row: LN stats for both; query row-sumexp; col-sumexp partials -> atomics.
__global__ __launch_bounds__(256) void mg_k1_stats(const float* __restrict__ x1, const float* __restrict__ x2,
                                                   const float* __restrict__ g1, const float* __restrict__ b1,
                                                   float* __restrict__ ws)
{
    float* mu1    = ws + OFF_MU1;
    float* rstd1  = ws + OFF_RSTD1;
    float* mu2    = ws + OFF_MU2;
    float* rstd2  = ws + OFF_RSTD2;
    float* rowinv = ws + OFF_ROWINV;
    float* colsum = ws + OFF_COLSUM;

    int t = threadIdx.x, lane = t & 63, w = t >> 6;
    int b = blockIdx.x / 144, rb = blockIdx.x % 144;
    int nbase = rb * 64;

    float4 g1v = ((const float4*)g1)[lane];
    float4 b1v = ((const float4*)b1)[lane];
    float cs0 = 0.f, cs1 = 0.f, cs2 = 0.f, cs3 = 0.f;
    __shared__ float csL[4][256];

    for (int i = 0; i < 16; ++i) {
        int n = nbase + i * 4 + w;
        int base = (b * Nn + n) * 64 + lane;
        float4 xa = ((const float4*)x1)[base];
        float4 xb = ((const float4*)x2)[base];
        float s1 = xa.x + xa.y + xa.z + xa.w;
        float q1 = xa.x*xa.x + xa.y*xa.y + xa.z*xa.z + xa.w*xa.w;
        float s2 = xb.x + xb.y + xb.z + xb.w;
        float q2 = xb.x*xb.x + xb.y*xb.y + xb.z*xb.z + xb.w*xb.w;
        #pragma unroll
        for (int m = 1; m < 64; m <<= 1) {
            s1 += __shfl_xor(s1, m); q1 += __shfl_xor(q1, m);
            s2 += __shfl_xor(s2, m); q2 += __shfl_xor(q2, m);
        }
        float m1 = s1 * (1.f / Dd), m2 = s2 * (1.f / Dd);
        float r1 = rsqrtf(q1 * (1.f / Dd) - m1 * m1 + EPSc);
        float r2 = rsqrtf(q2 * (1.f / Dd) - m2 * m2 + EPSc);
        int ni = b * Nn + n;
        if (lane == 0) { mu1[ni] = m1; rstd1[ni] = r1; mu2[ni] = m2; rstd2[ni] = r2; }
        // LN(x2) values are bounded -> exp without max-subtraction is safe in f32
        float e0 = __expf((xb.x - m2) * r2 * g1v.x + b1v.x);
        float e1 = __expf((xb.y - m2) * r2 * g1v.y + b1v.y);
        float e2 = __expf((xb.z - m2) * r2 * g1v.z + b1v.z);
        float e3 = __expf((xb.w - m2) * r2 * g1v.w + b1v.w);
        float rs = e0 + e1 + e2 + e3;
        #pragma unroll
        for (int m = 1; m < 64; m <<= 1) rs += __shfl_xor(rs, m);
        if (lane == 0) rowinv[ni] = 1.f / rs;
        cs0 += e0; cs1 += e1; cs2 += e2; cs3 += e3;
    }
    csL[w][lane * 4 + 0] = cs0;
    csL[w][lane * 4 + 1] = cs1;
    csL[w][lane * 4 + 2] = cs2;
    csL[w][lane * 4 + 3] = cs3;
    __syncthreads();
    float tot = csL[0][t] + csL[1][t] + csL[2][t] + csL[3][t];
    atomicAdd(&colsum[b * Dd + t], tot);
}

// K3: ctx_partial[p][b][d][e] = sum_{n in slice p} exp(n2[n][d]) * n1[n][e]
// grid: b(8) x ks(nks) x 8 tiles (4 db x 2 eb); block tile 64d x 128e; thread 4d x 8e.
__global__ __launch_bounds__(256, 4) void mg_k3_ctx(const float* __restrict__ x1, const float* __restrict__ x2,
                                                    const float* __restrict__ g1, const float* __restrict__ b1,
                                                    float* __restrict__ ws, int nks)
{
    __shared__ float vL[32 * 128];   // n1 tile [32n][128e], float4-deinterleaved slots
    __shared__ float aL[32 * 64];    // exp(n2) tile [32n][64d]
    __shared__ float g1s[256], b1s[256];
    const float* mu1   = ws + OFF_MU1;
    const float* rstd1 = ws + OFF_RSTD1;
    const float* mu2   = ws + OFF_MU2;
    const float* rstd2 = ws + OFF_RSTD2;
    float* ctxp = ws + OFF_CTXP;

    int t = threadIdx.x;
    int bid = blockIdx.x;
    int tile = bid & 7;
    int db = tile >> 1, eb = tile & 1;
    int ks_i = (bid >> 3) % nks;
    int b = bid / (8 * nks);
    int d0 = db * 64, e0 = eb * 128;
    int krange = Nn / nks;
    int nst = krange >> 5;
    int n_base = ks_i * krange;

    g1s[t] = g1[t]; b1s[t] = b1[t];

    float4* vL4 = (float4*)vL;
    float4* aL4 = (float4*)aL;

    int tx = t & 15, ty = t >> 4;
    int vrow = t >> 5, vq = t & 31;
    int arow = t >> 4, aq = t & 15;
    int vdst = ((vq & 1) << 4) | (vq >> 1);   // de-interleave: even q -> 0..15, odd -> 16..31

    float acc[4][8];
    #pragma unroll
    for (int i = 0; i < 4; ++i)
        #pragma unroll
        for (int j = 0; j < 8; ++j) acc[i][j] = 0.f;

    for (int st = 0; st < nst; ++st) {
        int r0 = n_base + st * 32;
        __syncthreads();
        #pragma unroll
        for (int k = 0; k < 4; ++k) {
            int row = vrow + k * 8;
            int ni = b * Nn + r0 + row;
            float4 xv = ((const float4*)x1)[(size_t)ni * 64 + (e0 >> 2) + vq];
            float m = mu1[ni], r = rstd1[ni];
            int c = e0 + vq * 4;
            float4 o;
            o.x = (xv.x - m) * r * g1s[c + 0] + b1s[c + 0];
            o.y = (xv.y - m) * r * g1s[c + 1] + b1s[c + 1];
            o.z = (xv.z - m) * r * g1s[c + 2] + b1s[c + 2];
            o.w = (xv.w - m) * r * g1s[c + 3] + b1s[c + 3];
            vL4[row * 32 + vdst] = o;
        }
        #pragma unroll
        for (int k = 0; k < 2; ++k) {
            int row = arow + k * 16;
            int ni = b * Nn + r0 + row;
            float4 xv = ((const float4*)x2)[(size_t)ni * 64 + (d0 >> 2) + aq];
            float m = mu2[ni], r = rstd2[ni];
            int c = d0 + aq * 4;
            float4 o;
            o.x = __expf((xv.x - m) * r * g1s[c + 0] + b1s[c + 0]);
            o.y = __expf((xv.y - m) * r * g1s[c + 1] + b1s[c + 1]);
            o.z = __expf((xv.z - m) * r * g1s[c + 2] + b1s[c + 2]);
            o.w = __expf((xv.w - m) * r * g1s[c + 3] + b1s[c + 3]);
            aL4[row * 16 + aq] = o;
        }
        __syncthreads();
        #pragma unroll 4
        for (int n = 0; n < 32; ++n) {
            float4 av = aL4[n * 16 + ty];
            float4 va = vL4[n * 32 + tx];
            float4 vb = vL4[n * 32 + 16 + tx];
            float A[4] = {av.x, av.y, av.z, av.w};
            float V[8] = {va.x, va.y, va.z, va.w, vb.x, vb.y, vb.z, vb.w};
            #pragma unroll
            for (int i = 0; i < 4; ++i)
                #pragma unroll
                for (int j = 0; j < 8; ++j)
                    acc[i][j] = fmaf(A[i], V[j], acc[i][j]);
        }
    }
    size_t obase = ((size_t)ks_i * Bc + b) * (Dd * Dd);
    #pragma unroll
    for (int i = 0; i < 4; ++i) {
        int d = d0 + ty * 4 + i;
        float* rp = ctxp + obase + (size_t)d * Dd + e0 + tx * 8;
        *(float4*)rp       = make_float4(acc[i][0], acc[i][1], acc[i][2], acc[i][3]);
        *(float4*)(rp + 4) = make_float4(acc[i][4], acc[i][5], acc[i][6], acc[i][7]);
    }
}

// K5: reduce ctx partials, scale by 1/colsum, bitonic sort (desc), 4 top-k thresholds,
// combined masked softmax M = sum_i a_i * softmax_masked_i.  grid = B*D rows.
__global__ __launch_bounds__(256) void mg_k5_mask(const float* __restrict__ a1p, const float* __restrict__ a2p,
                                                  const float* __restrict__ a3p, const float* __restrict__ a4p,
                                                  float* __restrict__ ws, int nks)
{
    const float* ctxp   = ws + OFF_CTXP;
    const float* colsum = ws + OFF_COLSUM;
    float* Mo = ws + OFF_M;
    int t = threadIdx.x;
    int b = blockIdx.x >> 8, d = blockIdx.x & 255;
    __shared__ float s[256];
    __shared__ float wred[4][4];

    float c = 0.f;
    for (int p = 0; p < nks; ++p)
        c += ctxp[((size_t)p * Bc + b) * (Dd * Dd) + (size_t)d * Dd + t];
    float inv = 1.f / colsum[b * Dd + d];
    c *= inv;
    s[t] = c;
    __syncthreads();
    for (int k = 2; k <= 256; k <<= 1) {
        for (int j = k >> 1; j > 0; j >>= 1) {
            int ixj = t ^ j;
            if (ixj > t) {
                float A = s[t], Bv = s[ixj];
                bool desc = ((t & k) == 0);
                bool sw = desc ? (A < Bv) : (A > Bv);
                if (sw) { s[t] = Bv; s[ixj] = A; }
            }
            __syncthreads();
        }
    }
    float cmax = s[0];
    float t0 = s[127], t1 = s[169], t2 = s[191], t3 = s[203];  // k-1 for k = 128,170,192,204
    float e = __expf(c - cmax);
    float w0 = (c >= t0) ? e : 0.f;
    float w1 = (c >= t1) ? e : 0.f;
    float w2 = (c >= t2) ? e : 0.f;
    float w3 = (c >= t3) ? e : 0.f;
    float v0 = w0, v1 = w1, v2 = w2, v3 = w3;
    #pragma unroll
    for (int m = 1; m < 64; m <<= 1) {
        v0 += __shfl_xor(v0, m); v1 += __shfl_xor(v1, m);
        v2 += __shfl_xor(v2, m); v3 += __shfl_xor(v3, m);
    }
    int lane = t & 63, wv = t >> 6;
    if (lane == 0) { wred[wv][0] = v0; wred[wv][1] = v1; wred[wv][2] = v2; wred[wv][3] = v3; }
    __syncthreads();
    float S0 = wred[0][0] + wred[1][0] + wred[2][0] + wred[3][0];
    float S1 = wred[0][1] + wred[1][1] + wred[2][1] + wred[3][1];
    float S2 = wred[0][2] + wred[1][2] + wred[2][2] + wred[3][2];
    float S3 = wred[0][3] + wred[1][3] + wred[2][3] + wred[3][3];
    float Mv = a1p[0] * (w0 / S0) + a2p[0] * (w1 / S1) + a3p[0] * (w2 / S2) + a4p[0] * (w3 / S3);
    Mo[(b * Dd + d) * Dd + t] = Mv;
}

// K6: W2[b][o][e] = sum_c Wr[o][c] * M[b][c][e], stored bf16 row-major [o][e] (MFMA A-ready).
// grid: b(8) x ob(16,o-32) x eh(2,e-128)
__global__ __launch_bounds__(256) void mg_k6_w2(const float* __restrict__ Wr, float* __restrict__ ws)
{
    const float* Mo = ws + OFF_M;
    ushort* W2B = (ushort*)(ws + OFF_W2T);
    __shared__ float Mt[32][128];
    __shared__ float WrT[32][36];
    int t = threadIdx.x;
    int b = blockIdx.x >> 5, ob = (blockIdx.x >> 1) & 15, eh = blockIdx.x & 1;
    int o0 = ob * 32, e0 = eh * 128;
    int ol4 = t & 7, el = t >> 3;   // o = o0+4*ol4+i, e = e0+4*el+j
    float acc[4][4];
    #pragma unroll
    for (int i = 0; i < 4; ++i)
        #pragma unroll
        for (int j = 0; j < 4; ++j) acc[i][j] = 0.f;

    for (int ch = 0; ch < 8; ++ch) {
        int c0 = ch * 32;
        __syncthreads();
        #pragma unroll
        for (int k = 0; k < 4; ++k) {
            int fi = t + k * 256;
            int row = fi >> 5, c4 = fi & 31;
            float4 mv = ((const float4*)Mo)[(b * Dd + c0 + row) * 64 + (e0 >> 2) + c4];
            *(float4*)&Mt[row][c4 * 4] = mv;
        }
        {
            int ol = t >> 3, c4 = t & 7;
            float4 wv = ((const float4*)Wr)[(o0 + ol) * 64 + (c0 >> 2) + c4];
            WrT[c4 * 4 + 0][ol] = wv.x;
            WrT[c4 * 4 + 1][ol] = wv.y;
            WrT[c4 * 4 + 2][ol] = wv.z;
            WrT[c4 * 4 + 3][ol] = wv.w;
        }
        __syncthreads();
        #pragma unroll
        for (int cc = 0; cc < 32; ++cc) {
            float4 w4 = *(const float4*)&WrT[cc][ol4 * 4];
            float4 m4 = *(const float4*)&Mt[cc][el * 4];
            float wv[4] = {w4.x, w4.y, w4.z, w4.w};
            float mv[4] = {m4.x, m4.y, m4.z, m4.w};
            #pragma unroll
            for (int i = 0; i < 4; ++i)
                #pragma unroll
                for (int j = 0; j < 4; ++j)
                    acc[i][j] = fmaf(wv[i], mv[j], acc[i][j]);
        }
    }
    #pragma unroll
    for (int i = 0; i < 4; ++i) {
        int o = o0 + ol4 * 4 + i;
        ushort4 u;
        u.x = f2bf(acc[i][0]); u.y = f2bf(acc[i][1]);
        u.z = f2bf(acc[i][2]); u.w = f2bf(acc[i][3]);
        *(ushort4*)&W2B[((size_t)b * Oo + o) * Dd + e0 + el * 4] = u;
    }
}

// K7 (MFMA): out[b][o][n0+n] = LN_o( sum_e W2[o][e] * q[e][n] + br[o] ) * g2 + b2
// block: 512o x 32n, 4 waves (wave w: o in [w*128, w*128+128)); 16x16x32 bf16 MFMA, 8 K-steps.
__global__ __launch_bounds__(256, 3) void mg_k7_final(const float* __restrict__ x2,
        const float* __restrict__ g1, const float* __restrict__ b1,
        const float* __restrict__ br, const float* __restrict__ g2, const float* __restrict__ b2,
        const float* __restrict__ ws, float* __restrict__ out)
{
    __shared__ ushort qsT[32 * 256];          // q^T tile [n][e] bf16, 16B-granule XOR swizzle
    __shared__ float g1s[256], b1s[256];
    __shared__ float stat[4][2][16][2];
    __shared__ float musig[32][2];

    const float* mu2    = ws + OFF_MU2;
    const float* rstd2  = ws + OFF_RSTD2;
    const float* rowinv = ws + OFF_ROWINV;
    const ushort* W2B   = (const ushort*)(ws + OFF_W2T);

    int t = threadIdx.x;
    int b = blockIdx.x / 288, nt0 = blockIdx.x % 288;
    int n0 = nt0 * 32;
    g1s[t] = g1[t]; b1s[t] = b1[t];
    __syncthreads();

    // stage q^T: q[e][n] = exp(LN(x2[n])[e]) * rowinv[n], stored n-major bf16
    #pragma unroll
    for (int k = 0; k < 4; ++k) {
        int fi = t + k * 256;
        int row = fi >> 5, g = fi & 31;       // row = n-local, g = e-granule (8 elems)
        int ni = b * Nn + n0 + row;
        float m = mu2[ni], r = rstd2[ni], ri = rowinv[ni];
        const float4* xp = (const float4*)x2 + (size_t)ni * 64 + g * 2;
        float4 xa = xp[0], xb = xp[1];
        int e = g * 8;
        float v[8] = {xa.x, xa.y, xa.z, xa.w, xb.x, xb.y, xb.z, xb.w};
        ushort8 u;
        #pragma unroll
        for (int j = 0; j < 8; ++j)
            u[j] = f2bf(__expf((v[j] - m) * r * g1s[e + j] + b1s[e + j]) * ri);
        *(ushort8*)&qsT[row * 256 + ((g ^ (row & 7)) << 3)] = u;
    }
    __syncthreads();

    int lw = t & 63, wave = t >> 6;
    int colA = lw & 15, kgrp = lw >> 4;

    f32x4 acc[8][2];
    #pragma unroll
    for (int ot = 0; ot < 8; ++ot) {
        acc[ot][0] = (f32x4){0.f, 0.f, 0.f, 0.f};
        acc[ot][1] = (f32x4){0.f, 0.f, 0.f, 0.f};
    }

    // A: W2B[b][o = wave*128 + ot*16 + colA][e = ks*32 + kgrp*8 + j]
    const ushort* abase = W2B + ((size_t)b * Oo + wave * 128 + colA) * Dd + kgrp * 8;

    for (int ks = 0; ks < 8; ++ks) {
        int g = ks * 4 + kgrp;
        int gs = (g ^ (colA & 7)) << 3;
        short8 bf0 = *(const short8*)&qsT[(colA) * 256 + gs];
        short8 bf1 = *(const short8*)&qsT[(16 + colA) * 256 + gs];
        #pragma unroll
        for (int ot = 0; ot < 8; ++ot) {
            short8 af = *(const short8*)&abase[(size_t)ot * 16 * Dd + ks * 32];
            acc[ot][0] = __builtin_amdgcn_mfma_f32_16x16x32_bf16(af, bf0, acc[ot][0], 0, 0, 0);
            acc[ot][1] = __builtin_amdgcn_mfma_f32_16x16x32_bf16(af, bf1, acc[ot][1], 0, 0, 0);
        }
    }

    // epilogue: +br, LN over 512 o per n, store transposed
    float ps[2] = {0.f, 0.f}, pq[2] = {0.f, 0.f};
    #pragma unroll
    for (int ot = 0; ot < 8; ++ot) {
        #pragma unroll
        for (int r = 0; r < 4; ++r) {
            int o = wave * 128 + ot * 16 + kgrp * 4 + r;
            float bb = br[o];
            float v0 = acc[ot][0][r] + bb;
            float v1 = acc[ot][1][r] + bb;
            acc[ot][0][r] = v0; acc[ot][1][r] = v1;
            ps[0] += v0; pq[0] += v0 * v0;
            ps[1] += v1; pq[1] += v1 * v1;
        }
    }
    #pragma unroll
    for (int m = 16; m <= 32; m <<= 1) {
        ps[0] += __shfl_xor(ps[0], m); pq[0] += __shfl_xor(pq[0], m);
        ps[1] += __shfl_xor(ps[1], m); pq[1] += __shfl_xor(pq[1], m);
    }
    if (lw < 16) {
        stat[wave][0][lw][0] = ps[0]; stat[wave][0][lw][1] = pq[0];
        stat[wave][1][lw][0] = ps[1]; stat[wave][1][lw][1] = pq[1];
    }
    __syncthreads();
    if (t < 32) {
        int ntile = t >> 4, col = t & 15;
        float S = 0.f, Q = 0.f;
        #pragma unroll
        for (int w2 = 0; w2 < 4; ++w2) { S += stat[w2][ntile][col][0]; Q += stat[w2][ntile][col][1]; }
        float mu = S * (1.f / Oo);
        float var = Q * (1.f / Oo) - mu * mu;
        musig[t][0] = mu;
        musig[t][1] = rsqrtf(var + EPSc);
    }
    __syncthreads();

    float mn0 = musig[colA][0],      rs0 = musig[colA][1];
    float mn1 = musig[16 + colA][0], rs1 = musig[16 + colA][1];
    #pragma unroll
    for (int ot = 0; ot < 8; ++ot) {
        #pragma unroll
        for (int r = 0; r < 4; ++r) {
            int o = wave * 128 + ot * 16 + kgrp * 4 + r;
            float gg = g2[o], bb2 = b2[o];
            size_t ob = ((size_t)b * Oo + o) * Nn + n0;
            out[ob + colA]      = (acc[ot][0][r] - mn0) * rs0 * gg + bb2;
            out[ob + 16 + colA] = (acc[ot][1][r] - mn1) * rs1 * gg + bb2;
        }
    }
}

extern "C" void kernel_launch(void* const* d_in, const int* in_sizes, int n_in,
                              void* d_out, int out_size, void* d_ws, size_t ws_size,
                              hipStream_t stream)
{
    (void)in_sizes; (void)n_in; (void)out_size;
    const float* x1 = (const float*)d_in[0];
    const float* x2 = (const float*)d_in[1];
    const float* g1 = (const float*)d_in[2];
    const float* b1 = (const float*)d_in[3];
    const float* Wr = (const float*)d_in[4];
    const float* br = (const float*)d_in[5];
    const float* g2 = (const float*)d_in[6];
    const float* b2 = (const float*)d_in[7];
    const float* a1 = (const float*)d_in[8];
    const float* a2 = (const float*)d_in[9];
    const float* a3 = (const float*)d_in[10];
    const float* a4 = (const float*)d_in[11];
    float* ws = (float*)d_ws;
    float* out = (float*)d_out;

    // adaptive split-K count: partials must fit in workspace
    int nks = 16;
    while (nks > 1 && (2467840ull + (size_t)nks * 524288ull) * 4ull > ws_size) nks >>= 1;

    hipLaunchKernelGGL(mg_k0_zero, dim3(2), dim3(256), 0, stream, ws + OFF_COLSUM, 512);
    hipLaunchKernelGGL(mg_k1_stats, dim3(1152), dim3(256), 0, stream, x1, x2, g1, b1, ws);
    hipLaunchKernelGGL(mg_k3_ctx, dim3(Bc * nks * 8), dim3(256), 0, stream, x1, x2, g1, b1, ws, nks);
    hipLaunchKernelGGL(mg_k5_mask, dim3(2048), dim3(256), 0, stream, a1, a2, a3, a4, ws, nks);
    hipLaunchKernelGGL(mg_k6_w2, dim3(256), dim3(256), 0, stream, Wr, ws);
    hipLaunchKernelGGL(mg_k7_final, dim3(2304), dim3(256), 0, stream, x2, g1, b1, br, g2, b2, ws, out);
}

// Round 5
// 229.438 us; speedup vs baseline: 3.8427x; 1.3903x over previous
//
#include <hip/hip_runtime.h>
#include <hip/hip_bf16.h>

#define Bc 8
#define Nn 9216
#define Dd 256
#define Oo 512
#define EPSc 1e-5f

// workspace float offsets
#define OFF_MU1    0
#define OFF_RSTD1  73728
#define OFF_MU2    147456
#define OFF_RSTD2  221184
#define OFF_ROWINV 294912
#define OFF_COLSUM 368640
#define OFF_M      894976
#define OFF_W2T    1419264   // W2 bf16 [b][o][e] = 2 MB (524288 float slots)
#define OFF_CTXP   2467840   // nks * 524288 floats of ctx partials (adaptive)

typedef __attribute__((ext_vector_type(4))) float f32x4;
typedef __attribute__((ext_vector_type(8))) short short8;
typedef __attribute__((ext_vector_type(8))) unsigned short ushort8;

static __device__ __forceinline__ unsigned short f2bf(float f) {
    __hip_bfloat16 h = __float2bfloat16(f);
    union { __hip_bfloat16 hh; unsigned short uu; } cv; cv.hh = h;
    return cv.uu;
}

// granule swizzle for channel-major bf16 tiles [ch][64n]: write conflict-free, read ~2-way
#define SWZ(ch) (((((ch) >> 2) & 7)) ^ ((((ch) & 3)) << 1))

__global__ __launch_bounds__(256) void mg_k0_zero(float* __restrict__ p, int n4) {
    int i = blockIdx.x * 256 + threadIdx.x;
    if (i < n4) ((float4*)p)[i] = make_float4(0.f, 0.f, 0.f, 0.f);
}

// K1: one pass over x1,x2. Per row: LN stats for both; query row-sumexp; col-sumexp partials -> atomics.
__global__ __launch_bounds__(256) void mg_k1_stats(const float* __restrict__ x1, const float* __restrict__ x2,
                                                   const float* __restrict__ g1, const float* __restrict__ b1,
                                                   float* __restrict__ ws)
{
    float* mu1    = ws + OFF_MU1;
    float* rstd1  = ws + OFF_RSTD1;
    float* mu2    = ws + OFF_MU2;
    float* rstd2  = ws + OFF_RSTD2;
    float* rowinv = ws + OFF_ROWINV;
    float* colsum = ws + OFF_COLSUM;

    int t = threadIdx.x, lane = t & 63, w = t >> 6;
    int b = blockIdx.x / 144, rb = blockIdx.x % 144;
    int nbase = rb * 64;

    float4 g1v = ((const float4*)g1)[lane];
    float4 b1v = ((const float4*)b1)[lane];
    float cs0 = 0.f, cs1 = 0.f, cs2 = 0.f, cs3 = 0.f;
    __shared__ float csL[4][256];

    for (int i = 0; i < 16; ++i) {
        int n = nbase + i * 4 + w;
        int base = (b * Nn + n) * 64 + lane;
        float4 xa = ((const float4*)x1)[base];
        float4 xb = ((const float4*)x2)[base];
        float s1 = xa.x + xa.y + xa.z + xa.w;
        float q1 = xa.x*xa.x + xa.y*xa.y + xa.z*xa.z + xa.w*xa.w;
        float s2 = xb.x + xb.y + xb.z + xb.w;
        float q2 = xb.x*xb.x + xb.y*xb.y + xb.z*xb.z + xb.w*xb.w;
        #pragma unroll
        for (int m = 1; m < 64; m <<= 1) {
            s1 += __shfl_xor(s1, m); q1 += __shfl_xor(q1, m);
            s2 += __shfl_xor(s2, m); q2 += __shfl_xor(q2, m);
        }
        float m1 = s1 * (1.f / Dd), m2 = s2 * (1.f / Dd);
        float r1 = rsqrtf(q1 * (1.f / Dd) - m1 * m1 + EPSc);
        float r2 = rsqrtf(q2 * (1.f / Dd) - m2 * m2 + EPSc);
        int ni = b * Nn + n;
        if (lane == 0) { mu1[ni] = m1; rstd1[ni] = r1; mu2[ni] = m2; rstd2[ni] = r2; }
        float e0 = __expf((xb.x - m2) * r2 * g1v.x + b1v.x);
        float e1 = __expf((xb.y - m2) * r2 * g1v.y + b1v.y);
        float e2 = __expf((xb.z - m2) * r2 * g1v.z + b1v.z);
        float e3 = __expf((xb.w - m2) * r2 * g1v.w + b1v.w);
        float rs = e0 + e1 + e2 + e3;
        #pragma unroll
        for (int m = 1; m < 64; m <<= 1) rs += __shfl_xor(rs, m);
        if (lane == 0) rowinv[ni] = 1.f / rs;
        cs0 += e0; cs1 += e1; cs2 += e2; cs3 += e3;
    }
    csL[w][lane * 4 + 0] = cs0;
    csL[w][lane * 4 + 1] = cs1;
    csL[w][lane * 4 + 2] = cs2;
    csL[w][lane * 4 + 3] = cs3;
    __syncthreads();
    float tot = csL[0][t] + csL[1][t] + csL[2][t] + csL[3][t];
    atomicAdd(&colsum[b * Dd + t], tot);
}

// K3 v4 (MFMA): ctx_partial[p][b][d][e] = sum_{n in slice p} exp(n2[n][d]) * n1[n][e]
// grid: b(8) x ks(nks); block 512 thr (8 waves), tile 256d x 256e, K-tile 64 n.
// LDS channel-major bf16 tiles PA[256d][64n], PB[256e][64n]; staging does the
// transpose in registers (8n x 4ch micro-tile per thread -> b128 writes).
__global__ __launch_bounds__(512, 2) void mg_k3_ctx(const float* __restrict__ x1, const float* __restrict__ x2,
                                                    const float* __restrict__ g1, const float* __restrict__ b1,
                                                    float* __restrict__ ws, int nks)
{
    __shared__ ushort PA[256 * 64];   // exp(n2): [d][n]
    __shared__ ushort PB[256 * 64];   // n1:      [e][n]
    const float* mu1   = ws + OFF_MU1;
    const float* rstd1 = ws + OFF_RSTD1;
    const float* mu2   = ws + OFF_MU2;
    const float* rstd2 = ws + OFF_RSTD2;
    float* ctxp = ws + OFF_CTXP;

    int t = threadIdx.x;
    int ks_i = blockIdx.x % nks;
    int b = blockIdx.x / nks;
    int krange = Nn / nks;
    int ntiles = krange >> 6;
    int n_base = ks_i * krange;

    int o  = t >> 6;     // n-octet (= wave id), rows o*8..o*8+7
    int c4 = t & 63;     // channel quad: ch = c4*4 + i

    f32x4 g1v = ((const f32x4*)g1)[c4];
    f32x4 b1v = ((const f32x4*)b1)[c4];

    int lane = t & 63, wave = t >> 6;
    int wd = wave & 3, we = wave >> 2;     // wave tile: 64d x 128e
    int l15 = lane & 15, kgrp = lane >> 4;

    f32x4 acc[4][8];
    #pragma unroll
    for (int dt = 0; dt < 4; ++dt)
        #pragma unroll
        for (int et = 0; et < 8; ++et) acc[dt][et] = (f32x4){0.f, 0.f, 0.f, 0.f};

    for (int st = 0; st < ntiles; ++st) {
        int rowb = b * Nn + n_base + st * 64 + o * 8;
        __syncthreads();
        // x1 -> PB (LayerNorm values, bf16)
        {
            f32x4 mv0 = *(const f32x4*)(mu1 + rowb),   mv1 = *(const f32x4*)(mu1 + rowb + 4);
            f32x4 rv0 = *(const f32x4*)(rstd1 + rowb), rv1 = *(const f32x4*)(rstd1 + rowb + 4);
            float mva[8] = {mv0[0], mv0[1], mv0[2], mv0[3], mv1[0], mv1[1], mv1[2], mv1[3]};
            float rva[8] = {rv0[0], rv0[1], rv0[2], rv0[3], rv1[0], rv1[1], rv1[2], rv1[3]};
            f32x4 xv[8];
            #pragma unroll
            for (int rr = 0; rr < 8; ++rr)
                xv[rr] = ((const f32x4*)x1)[(size_t)(rowb + rr) * 64 + c4];
            #pragma unroll
            for (int i = 0; i < 4; ++i) {
                int ch = c4 * 4 + i;
                ushort8 u;
                #pragma unroll
                for (int rr = 0; rr < 8; ++rr)
                    u[rr] = f2bf((xv[rr][i] - mva[rr]) * rva[rr] * g1v[i] + b1v[i]);
                *(ushort8*)&PB[ch * 64 + ((o + SWZ(ch)) & 7) * 8] = u;
            }
        }
        // x2 -> PA (exp(LayerNorm), bf16)
        {
            f32x4 mv0 = *(const f32x4*)(mu2 + rowb),   mv1 = *(const f32x4*)(mu2 + rowb + 4);
            f32x4 rv0 = *(const f32x4*)(rstd2 + rowb), rv1 = *(const f32x4*)(rstd2 + rowb + 4);
            float mva[8] = {mv0[0], mv0[1], mv0[2], mv0[3], mv1[0], mv1[1], mv1[2], mv1[3]};
            float rva[8] = {rv0[0], rv0[1], rv0[2], rv0[3], rv1[0], rv1[1], rv1[2], rv1[3]};
            f32x4 xv[8];
            #pragma unroll
            for (int rr = 0; rr < 8; ++rr)
                xv[rr] = ((const f32x4*)x2)[(size_t)(rowb + rr) * 64 + c4];
            #pragma unroll
            for (int i = 0; i < 4; ++i) {
                int ch = c4 * 4 + i;
                ushort8 u;
                #pragma unroll
                for (int rr = 0; rr < 8; ++rr)
                    u[rr] = f2bf(__expf((xv[rr][i] - mva[rr]) * rva[rr] * g1v[i] + b1v[i]));
                *(ushort8*)&PA[ch * 64 + ((o + SWZ(ch)) & 7) * 8] = u;
            }
        }
        __syncthreads();

        #pragma unroll
        for (int kk = 0; kk < 2; ++kk) {
            short8 af[4], bf[8];
            #pragma unroll
            for (int dt = 0; dt < 4; ++dt) {
                int ch = wd * 64 + dt * 16 + l15;
                af[dt] = *(const short8*)&PA[ch * 64 + (((kk << 2) + kgrp + SWZ(ch)) & 7) * 8];
            }
            #pragma unroll
            for (int et = 0; et < 8; ++et) {
                int ch = we * 128 + et * 16 + l15;
                bf[et] = *(const short8*)&PB[ch * 64 + (((kk << 2) + kgrp + SWZ(ch)) & 7) * 8];
            }
            #pragma unroll
            for (int dt = 0; dt < 4; ++dt)
                #pragma unroll
                for (int et = 0; et < 8; ++et)
                    acc[dt][et] = __builtin_amdgcn_mfma_f32_16x16x32_bf16(af[dt], bf[et], acc[dt][et], 0, 0, 0);
        }
    }

    size_t obase = ((size_t)ks_i * Bc + b) * (Dd * Dd);
    #pragma unroll
    for (int dt = 0; dt < 4; ++dt) {
        #pragma unroll
        for (int r = 0; r < 4; ++r) {
            int d = wd * 64 + dt * 16 + kgrp * 4 + r;
            float* rowp = ctxp + obase + (size_t)d * Dd + we * 128 + l15;
            #pragma unroll
            for (int et = 0; et < 8; ++et)
                rowp[et * 16] = acc[dt][et][r];
        }
    }
}

// K5: reduce ctx partials, scale by 1/colsum, bitonic sort (desc), 4 top-k thresholds,
// combined masked softmax M = sum_i a_i * softmax_masked_i.  grid = B*D rows.
__global__ __launch_bounds__(256) void mg_k5_mask(const float* __restrict__ a1p, const float* __restrict__ a2p,
                                                  const float* __restrict__ a3p, const float* __restrict__ a4p,
                                                  float* __restrict__ ws, int nks)
{
    const float* ctxp   = ws + OFF_CTXP;
    const float* colsum = ws + OFF_COLSUM;
    float* Mo = ws + OFF_M;
    int t = threadIdx.x;
    int b = blockIdx.x >> 8, d = blockIdx.x & 255;
    __shared__ float s[256];
    __shared__ float wred[4][4];

    float c = 0.f;
    for (int p = 0; p < nks; ++p)
        c += ctxp[((size_t)p * Bc + b) * (Dd * Dd) + (size_t)d * Dd + t];
    float inv = 1.f / colsum[b * Dd + d];
    c *= inv;
    s[t] = c;
    __syncthreads();
    for (int k = 2; k <= 256; k <<= 1) {
        for (int j = k >> 1; j > 0; j >>= 1) {
            int ixj = t ^ j;
            if (ixj > t) {
                float A = s[t], Bv = s[ixj];
                bool desc = ((t & k) == 0);
                bool sw = desc ? (A < Bv) : (A > Bv);
                if (sw) { s[t] = Bv; s[ixj] = A; }
            }
            __syncthreads();
        }
    }
    float cmax = s[0];
    float t0 = s[127], t1 = s[169], t2 = s[191], t3 = s[203];  // k-1 for k = 128,170,192,204
    float e = __expf(c - cmax);
    float w0 = (c >= t0) ? e : 0.f;
    float w1 = (c >= t1) ? e : 0.f;
    float w2 = (c >= t2) ? e : 0.f;
    float w3 = (c >= t3) ? e : 0.f;
    float v0 = w0, v1 = w1, v2 = w2, v3 = w3;
    #pragma unroll
    for (int m = 1; m < 64; m <<= 1) {
        v0 += __shfl_xor(v0, m); v1 += __shfl_xor(v1, m);
        v2 += __shfl_xor(v2, m); v3 += __shfl_xor(v3, m);
    }
    int lane = t & 63, wv = t >> 6;
    if (lane == 0) { wred[wv][0] = v0; wred[wv][1] = v1; wred[wv][2] = v2; wred[wv][3] = v3; }
    __syncthreads();
    float S0 = wred[0][0] + wred[1][0] + wred[2][0] + wred[3][0];
    float S1 = wred[0][1] + wred[1][1] + wred[2][1] + wred[3][1];
    float S2 = wred[0][2] + wred[1][2] + wred[2][2] + wred[3][2];
    float S3 = wred[0][3] + wred[1][3] + wred[2][3] + wred[3][3];
    float Mv = a1p[0] * (w0 / S0) + a2p[0] * (w1 / S1) + a3p[0] * (w2 / S2) + a4p[0] * (w3 / S3);
    Mo[(b * Dd + d) * Dd + t] = Mv;
}

// K6: W2[b][o][e] = sum_c Wr[o][c] * M[b][c][e], stored bf16 row-major [o][e] (MFMA A-ready).
__global__ __launch_bounds__(256) void mg_k6_w2(const float* __restrict__ Wr, float* __restrict__ ws)
{
    const float* Mo = ws + OFF_M;
    ushort* W2B = (ushort*)(ws + OFF_W2T);
    __shared__ float Mt[32][128];
    __shared__ float WrT[32][36];
    int t = threadIdx.x;
    int b = blockIdx.x >> 5, ob = (blockIdx.x >> 1) & 15, eh = blockIdx.x & 1;
    int o0 = ob * 32, e0 = eh * 128;
    int ol4 = t & 7, el = t >> 3;
    float acc[4][4];
    #pragma unroll
    for (int i = 0; i < 4; ++i)
        #pragma unroll
        for (int j = 0; j < 4; ++j) acc[i][j] = 0.f;

    for (int ch = 0; ch < 8; ++ch) {
        int c0 = ch * 32;
        __syncthreads();
        #pragma unroll
        for (int k = 0; k < 4; ++k) {
            int fi = t + k * 256;
            int row = fi >> 5, c4 = fi & 31;
            float4 mv = ((const float4*)Mo)[(b * Dd + c0 + row) * 64 + (e0 >> 2) + c4];
            *(float4*)&Mt[row][c4 * 4] = mv;
        }
        {
            int ol = t >> 3, c4 = t & 7;
            float4 wv = ((const float4*)Wr)[(o0 + ol) * 64 + (c0 >> 2) + c4];
            WrT[c4 * 4 + 0][ol] = wv.x;
            WrT[c4 * 4 + 1][ol] = wv.y;
            WrT[c4 * 4 + 2][ol] = wv.z;
            WrT[c4 * 4 + 3][ol] = wv.w;
        }
        __syncthreads();
        #pragma unroll
        for (int cc = 0; cc < 32; ++cc) {
            float4 w4 = *(const float4*)&WrT[cc][ol4 * 4];
            float4 m4 = *(const float4*)&Mt[cc][el * 4];
            float wv[4] = {w4.x, w4.y, w4.z, w4.w};
            float mv[4] = {m4.x, m4.y, m4.z, m4.w};
            #pragma unroll
            for (int i = 0; i < 4; ++i)
                #pragma unroll
                for (int j = 0; j < 4; ++j)
                    acc[i][j] = fmaf(wv[i], mv[j], acc[i][j]);
        }
    }
    #pragma unroll
    for (int i = 0; i < 4; ++i) {
        int o = o0 + ol4 * 4 + i;
        ushort4 u;
        u.x = f2bf(acc[i][0]); u.y = f2bf(acc[i][1]);
        u.z = f2bf(acc[i][2]); u.w = f2bf(acc[i][3]);
        *(ushort4*)&W2B[((size_t)b * Oo + o) * Dd + e0 + el * 4] = u;
    }
}

// K7 (MFMA): out[b][o][n0+n] = LN_o( sum_e W2[o][e] * q[e][n] + br[o] ) * g2 + b2
__global__ __launch_bounds__(256, 3) void mg_k7_final(const float* __restrict__ x2,
        const float* __restrict__ g1, const float* __restrict__ b1,
        const float* __restrict__ br, const float* __restrict__ g2, const float* __restrict__ b2,
        const float* __restrict__ ws, float* __restrict__ out)
{
    __shared__ ushort qsT[32 * 256];
    __shared__ float g1s[256], b1s[256];
    __shared__ float stat[4][2][16][2];
    __shared__ float musig[32][2];

    const float* mu2    = ws + OFF_MU2;
    const float* rstd2  = ws + OFF_RSTD2;
    const float* rowinv = ws + OFF_ROWINV;
    const ushort* W2B   = (const ushort*)(ws + OFF_W2T);

    int t = threadIdx.x;
    int b = blockIdx.x / 288, nt0 = blockIdx.x % 288;
    int n0 = nt0 * 32;
    g1s[t] = g1[t]; b1s[t] = b1[t];
    __syncthreads();

    #pragma unroll
    for (int k = 0; k < 4; ++k) {
        int fi = t + k * 256;
        int row = fi >> 5, g = fi & 31;
        int ni = b * Nn + n0 + row;
        float m = mu2[ni], r = rstd2[ni], ri = rowinv[ni];
        const float4* xp = (const float4*)x2 + (size_t)ni * 64 + g * 2;
        float4 xa = xp[0], xb = xp[1];
        int e = g * 8;
        float v[8] = {xa.x, xa.y, xa.z, xa.w, xb.x, xb.y, xb.z, xb.w};
        ushort8 u;
        #pragma unroll
        for (int j = 0; j < 8; ++j)
            u[j] = f2bf(__expf((v[j] - m) * r * g1s[e + j] + b1s[e + j]) * ri);
        *(ushort8*)&qsT[row * 256 + ((g ^ (row & 7)) << 3)] = u;
    }
    __syncthreads();

    int lw = t & 63, wave = t >> 6;
    int colA = lw & 15, kgrp = lw >> 4;

    f32x4 acc[8][2];
    #pragma unroll
    for (int ot = 0; ot < 8; ++ot) {
        acc[ot][0] = (f32x4){0.f, 0.f, 0.f, 0.f};
        acc[ot][1] = (f32x4){0.f, 0.f, 0.f, 0.f};
    }

    const ushort* abase = W2B + ((size_t)b * Oo + wave * 128 + colA) * Dd + kgrp * 8;

    for (int ks = 0; ks < 8; ++ks) {
        int g = ks * 4 + kgrp;
        int gs = (g ^ (colA & 7)) << 3;
        short8 bf0 = *(const short8*)&qsT[(colA) * 256 + gs];
        short8 bf1 = *(const short8*)&qsT[(16 + colA) * 256 + gs];
        #pragma unroll
        for (int ot = 0; ot < 8; ++ot) {
            short8 af = *(const short8*)&abase[(size_t)ot * 16 * Dd + ks * 32];
            acc[ot][0] = __builtin_amdgcn_mfma_f32_16x16x32_bf16(af, bf0, acc[ot][0], 0, 0, 0);
            acc[ot][1] = __builtin_amdgcn_mfma_f32_16x16x32_bf16(af, bf1, acc[ot][1], 0, 0, 0);
        }
    }

    float ps[2] = {0.f, 0.f}, pq[2] = {0.f, 0.f};
    #pragma unroll
    for (int ot = 0; ot < 8; ++ot) {
        #pragma unroll
        for (int r = 0; r < 4; ++r) {
            int o = wave * 128 + ot * 16 + kgrp * 4 + r;
            float bb = br[o];
            float v0 = acc[ot][0][r] + bb;
            float v1 = acc[ot][1][r] + bb;
            acc[ot][0][r] = v0; acc[ot][1][r] = v1;
            ps[0] += v0; pq[0] += v0 * v0;
            ps[1] += v1; pq[1] += v1 * v1;
        }
    }
    #pragma unroll
    for (int m = 16; m <= 32; m <<= 1) {
        ps[0] += __shfl_xor(ps[0], m); pq[0] += __shfl_xor(pq[0], m);
        ps[1] += __shfl_xor(ps[1], m); pq[1] += __shfl_xor(pq[1], m);
    }
    if (lw < 16) {
        stat[wave][0][lw][0] = ps[0]; stat[wave][0][lw][1] = pq[0];
        stat[wave][1][lw][0] = ps[1]; stat[wave][1][lw][1] = pq[1];
    }
    __syncthreads();
    if (t < 32) {
        int ntile = t >> 4, col = t & 15;
        float S = 0.f, Q = 0.f;
        #pragma unroll
        for (int w2 = 0; w2 < 4; ++w2) { S += stat[w2][ntile][col][0]; Q += stat[w2][ntile][col][1]; }
        float mu = S * (1.f / Oo);
        float var = Q * (1.f / Oo) - mu * mu;
        musig[t][0] = mu;
        musig[t][1] = rsqrtf(var + EPSc);
    }
    __syncthreads();

    float mn0 = musig[colA][0],      rs0 = musig[colA][1];
    float mn1 = musig[16 + colA][0], rs1 = musig[16 + colA][1];
    #pragma unroll
    for (int ot = 0; ot < 8; ++ot) {
        #pragma unroll
        for (int r = 0; r < 4; ++r) {
            int o = wave * 128 + ot * 16 + kgrp * 4 + r;
            float gg = g2[o], bb2 = b2[o];
            size_t ob = ((size_t)b * Oo + o) * Nn + n0;
            out[ob + colA]      = (acc[ot][0][r] - mn0) * rs0 * gg + bb2;
            out[ob + 16 + colA] = (acc[ot][1][r] - mn1) * rs1 * gg + bb2;
        }
    }
}

extern "C" void kernel_launch(void* const* d_in, const int* in_sizes, int n_in,
                              void* d_out, int out_size, void* d_ws, size_t ws_size,
                              hipStream_t stream)
{
    (void)in_sizes; (void)n_in; (void)out_size;
    const float* x1 = (const float*)d_in[0];
    const float* x2 = (const float*)d_in[1];
    const float* g1 = (const float*)d_in[2];
    const float* b1 = (const float*)d_in[3];
    const float* Wr = (const float*)d_in[4];
    const float* br = (const float*)d_in[5];
    const float* g2 = (const float*)d_in[6];
    const float* b2 = (const float*)d_in[7];
    const float* a1 = (const float*)d_in[8];
    const float* a2 = (const float*)d_in[9];
    const float* a3 = (const float*)d_in[10];
    const float* a4 = (const float*)d_in[11];
    float* ws = (float*)d_ws;
    float* out = (float*)d_out;

    // adaptive split-K: nks must divide 144 (so krange % 64 == 0) and partials must fit ws
    const int cand[6] = {24, 16, 12, 8, 4, 2};
    int nks = 2;
    for (int ci = 0; ci < 6; ++ci) {
        if ((2467840ull + (size_t)cand[ci] * 524288ull) * 4ull <= ws_size) { nks = cand[ci]; break; }
    }

    hipLaunchKernelGGL(mg_k0_zero, dim3(2), dim3(256), 0, stream, ws + OFF_COLSUM, 512);
    hipLaunchKernelGGL(mg_k1_stats, dim3(1152), dim3(256), 0, stream, x1, x2, g1, b1, ws);
    hipLaunchKernelGGL(mg_k3_ctx, dim3(Bc * nks), dim3(512), 0, stream, x1, x2, g1, b1, ws, nks);
    hipLaunchKernelGGL(mg_k5_mask, dim3(2048), dim3(256), 0, stream, a1, a2, a3, a4, ws, nks);
    hipLaunchKernelGGL(mg_k6_w2, dim3(256), dim3(256), 0, stream, Wr, ws);
    hipLaunchKernelGGL(mg_k7_final, dim3(2304), dim3(256), 0, stream, x2, g1, b1, br, g2, b2, ws, out);
}

// Round 6
// 216.791 us; speedup vs baseline: 4.0669x; 1.0583x over previous
//
#include <hip/hip_runtime.h>
#include <hip/hip_bf16.h>

#define Bc 8
#define Nn 9216
#define Dd 256
#define Oo 512
#define EPSc 1e-5f

// workspace float offsets
#define OFF_MU1    0
#define OFF_RSTD1  73728
#define OFF_MU2    147456
#define OFF_RSTD2  221184
#define OFF_ROWINV 294912
#define OFF_COLSUM 368640
#define OFF_M      894976
#define OFF_W2T    1419264   // W2 bf16 [b][o][e] = 2 MB (524288 float slots)
#define OFF_CTXP   2467840   // nks * 524288 floats of ctx partials (adaptive)

typedef __attribute__((ext_vector_type(4))) float f32x4;
typedef __attribute__((ext_vector_type(8))) short short8;
typedef __attribute__((ext_vector_type(8))) unsigned short ushort8;

static __device__ __forceinline__ unsigned short f2bf(float f) {
    __hip_bfloat16 h = __float2bfloat16(f);
    union { __hip_bfloat16 hh; unsigned short uu; } cv; cv.hh = h;
    return cv.uu;
}

// granule swizzle for channel-major bf16 tiles [ch][64n]: write conflict-free, read ~2-way
#define SWZ(ch) (((((ch) >> 2) & 7)) ^ ((((ch) & 3)) << 1))

__global__ __launch_bounds__(256) void mg_k0_zero(float* __restrict__ p, int n4) {
    int i = blockIdx.x * 256 + threadIdx.x;
    if (i < n4) ((float4*)p)[i] = make_float4(0.f, 0.f, 0.f, 0.f);
}

// K1: one pass over x1,x2. Per row: LN stats for both; query row-sumexp; col-sumexp partials -> atomics.
__global__ __launch_bounds__(256) void mg_k1_stats(const float* __restrict__ x1, const float* __restrict__ x2,
                                                   const float* __restrict__ g1, const float* __restrict__ b1,
                                                   float* __restrict__ ws)
{
    float* mu1    = ws + OFF_MU1;
    float* rstd1  = ws + OFF_RSTD1;
    float* mu2    = ws + OFF_MU2;
    float* rstd2  = ws + OFF_RSTD2;
    float* rowinv = ws + OFF_ROWINV;
    float* colsum = ws + OFF_COLSUM;

    int t = threadIdx.x, lane = t & 63, w = t >> 6;
    int b = blockIdx.x / 144, rb = blockIdx.x % 144;
    int nbase = rb * 64;

    float4 g1v = ((const float4*)g1)[lane];
    float4 b1v = ((const float4*)b1)[lane];
    float cs0 = 0.f, cs1 = 0.f, cs2 = 0.f, cs3 = 0.f;
    __shared__ float csL[4][256];

    for (int i = 0; i < 16; ++i) {
        int n = nbase + i * 4 + w;
        int base = (b * Nn + n) * 64 + lane;
        float4 xa = ((const float4*)x1)[base];
        float4 xb = ((const float4*)x2)[base];
        float s1 = xa.x + xa.y + xa.z + xa.w;
        float q1 = xa.x*xa.x + xa.y*xa.y + xa.z*xa.z + xa.w*xa.w;
        float s2 = xb.x + xb.y + xb.z + xb.w;
        float q2 = xb.x*xb.x + xb.y*xb.y + xb.z*xb.z + xb.w*xb.w;
        #pragma unroll
        for (int m = 1; m < 64; m <<= 1) {
            s1 += __shfl_xor(s1, m); q1 += __shfl_xor(q1, m);
            s2 += __shfl_xor(s2, m); q2 += __shfl_xor(q2, m);
        }
        float m1 = s1 * (1.f / Dd), m2 = s2 * (1.f / Dd);
        float r1 = rsqrtf(q1 * (1.f / Dd) - m1 * m1 + EPSc);
        float r2 = rsqrtf(q2 * (1.f / Dd) - m2 * m2 + EPSc);
        int ni = b * Nn + n;
        if (lane == 0) { mu1[ni] = m1; rstd1[ni] = r1; mu2[ni] = m2; rstd2[ni] = r2; }
        float e0 = __expf((xb.x - m2) * r2 * g1v.x + b1v.x);
        float e1 = __expf((xb.y - m2) * r2 * g1v.y + b1v.y);
        float e2 = __expf((xb.z - m2) * r2 * g1v.z + b1v.z);
        float e3 = __expf((xb.w - m2) * r2 * g1v.w + b1v.w);
        float rs = e0 + e1 + e2 + e3;
        #pragma unroll
        for (int m = 1; m < 64; m <<= 1) rs += __shfl_xor(rs, m);
        if (lane == 0) rowinv[ni] = 1.f / rs;
        cs0 += e0; cs1 += e1; cs2 += e2; cs3 += e3;
    }
    csL[w][lane * 4 + 0] = cs0;
    csL[w][lane * 4 + 1] = cs1;
    csL[w][lane * 4 + 2] = cs2;
    csL[w][lane * 4 + 3] = cs3;
    __syncthreads();
    float tot = csL[0][t] + csL[1][t] + csL[2][t] + csL[3][t];
    atomicAdd(&colsum[b * Dd + t], tot);
}

// K3 (MFMA): ctx_partial[p][b][d][e] = sum_{n in slice p} exp(n2[n][d]) * n1[n][e]
__global__ __launch_bounds__(512, 2) void mg_k3_ctx(const float* __restrict__ x1, const float* __restrict__ x2,
                                                    const float* __restrict__ g1, const float* __restrict__ b1,
                                                    float* __restrict__ ws, int nks)
{
    __shared__ ushort PA[256 * 64];   // exp(n2): [d][n]
    __shared__ ushort PB[256 * 64];   // n1:      [e][n]
    const float* mu1   = ws + OFF_MU1;
    const float* rstd1 = ws + OFF_RSTD1;
    const float* mu2   = ws + OFF_MU2;
    const float* rstd2 = ws + OFF_RSTD2;
    float* ctxp = ws + OFF_CTXP;

    int t = threadIdx.x;
    int ks_i = blockIdx.x % nks;
    int b = blockIdx.x / nks;
    int krange = Nn / nks;
    int ntiles = krange >> 6;
    int n_base = ks_i * krange;

    int o  = t >> 6;
    int c4 = t & 63;

    f32x4 g1v = ((const f32x4*)g1)[c4];
    f32x4 b1v = ((const f32x4*)b1)[c4];

    int lane = t & 63, wave = t >> 6;
    int wd = wave & 3, we = wave >> 2;
    int l15 = lane & 15, kgrp = lane >> 4;

    f32x4 acc[4][8];
    #pragma unroll
    for (int dt = 0; dt < 4; ++dt)
        #pragma unroll
        for (int et = 0; et < 8; ++et) acc[dt][et] = (f32x4){0.f, 0.f, 0.f, 0.f};

    for (int st = 0; st < ntiles; ++st) {
        int rowb = b * Nn + n_base + st * 64 + o * 8;
        __syncthreads();
        {
            f32x4 mv0 = *(const f32x4*)(mu1 + rowb),   mv1 = *(const f32x4*)(mu1 + rowb + 4);
            f32x4 rv0 = *(const f32x4*)(rstd1 + rowb), rv1 = *(const f32x4*)(rstd1 + rowb + 4);
            float mva[8] = {mv0[0], mv0[1], mv0[2], mv0[3], mv1[0], mv1[1], mv1[2], mv1[3]};
            float rva[8] = {rv0[0], rv0[1], rv0[2], rv0[3], rv1[0], rv1[1], rv1[2], rv1[3]};
            f32x4 xv[8];
            #pragma unroll
            for (int rr = 0; rr < 8; ++rr)
                xv[rr] = ((const f32x4*)x1)[(size_t)(rowb + rr) * 64 + c4];
            #pragma unroll
            for (int i = 0; i < 4; ++i) {
                int ch = c4 * 4 + i;
                ushort8 u;
                #pragma unroll
                for (int rr = 0; rr < 8; ++rr)
                    u[rr] = f2bf((xv[rr][i] - mva[rr]) * rva[rr] * g1v[i] + b1v[i]);
                *(ushort8*)&PB[ch * 64 + ((o + SWZ(ch)) & 7) * 8] = u;
            }
        }
        {
            f32x4 mv0 = *(const f32x4*)(mu2 + rowb),   mv1 = *(const f32x4*)(mu2 + rowb + 4);
            f32x4 rv0 = *(const f32x4*)(rstd2 + rowb), rv1 = *(const f32x4*)(rstd2 + rowb + 4);
            float mva[8] = {mv0[0], mv0[1], mv0[2], mv0[3], mv1[0], mv1[1], mv1[2], mv1[3]};
            float rva[8] = {rv0[0], rv0[1], rv0[2], rv0[3], rv1[0], rv1[1], rv1[2], rv1[3]};
            f32x4 xv[8];
            #pragma unroll
            for (int rr = 0; rr < 8; ++rr)
                xv[rr] = ((const f32x4*)x2)[(size_t)(rowb + rr) * 64 + c4];
            #pragma unroll
            for (int i = 0; i < 4; ++i) {
                int ch = c4 * 4 + i;
                ushort8 u;
                #pragma unroll
                for (int rr = 0; rr < 8; ++rr)
                    u[rr] = f2bf(__expf((xv[rr][i] - mva[rr]) * rva[rr] * g1v[i] + b1v[i]));
                *(ushort8*)&PA[ch * 64 + ((o + SWZ(ch)) & 7) * 8] = u;
            }
        }
        __syncthreads();

        #pragma unroll
        for (int kk = 0; kk < 2; ++kk) {
            short8 af[4], bf[8];
            #pragma unroll
            for (int dt = 0; dt < 4; ++dt) {
                int ch = wd * 64 + dt * 16 + l15;
                af[dt] = *(const short8*)&PA[ch * 64 + (((kk << 2) + kgrp + SWZ(ch)) & 7) * 8];
            }
            #pragma unroll
            for (int et = 0; et < 8; ++et) {
                int ch = we * 128 + et * 16 + l15;
                bf[et] = *(const short8*)&PB[ch * 64 + (((kk << 2) + kgrp + SWZ(ch)) & 7) * 8];
            }
            #pragma unroll
            for (int dt = 0; dt < 4; ++dt)
                #pragma unroll
                for (int et = 0; et < 8; ++et)
                    acc[dt][et] = __builtin_amdgcn_mfma_f32_16x16x32_bf16(af[dt], bf[et], acc[dt][et], 0, 0, 0);
        }
    }

    size_t obase = ((size_t)ks_i * Bc + b) * (Dd * Dd);
    #pragma unroll
    for (int dt = 0; dt < 4; ++dt) {
        #pragma unroll
        for (int r = 0; r < 4; ++r) {
            int d = wd * 64 + dt * 16 + kgrp * 4 + r;
            float* rowp = ctxp + obase + (size_t)d * Dd + we * 128 + l15;
            #pragma unroll
            for (int et = 0; et < 8; ++et)
                rowp[et * 16] = acc[dt][et][r];
        }
    }
}

// K5: reduce ctx partials, scale by 1/colsum, bitonic sort (desc), 4 top-k thresholds,
// combined masked softmax M = sum_i a_i * softmax_masked_i.  grid = B*D rows.
__global__ __launch_bounds__(256) void mg_k5_mask(const float* __restrict__ a1p, const float* __restrict__ a2p,
                                                  const float* __restrict__ a3p, const float* __restrict__ a4p,
                                                  float* __restrict__ ws, int nks)
{
    const float* ctxp   = ws + OFF_CTXP;
    const float* colsum = ws + OFF_COLSUM;
    float* Mo = ws + OFF_M;
    int t = threadIdx.x;
    int b = blockIdx.x >> 8, d = blockIdx.x & 255;
    __shared__ float s[256];
    __shared__ float wred[4][4];

    float c = 0.f;
    for (int p = 0; p < nks; ++p)
        c += ctxp[((size_t)p * Bc + b) * (Dd * Dd) + (size_t)d * Dd + t];
    float inv = 1.f / colsum[b * Dd + d];
    c *= inv;
    s[t] = c;
    __syncthreads();
    for (int k = 2; k <= 256; k <<= 1) {
        for (int j = k >> 1; j > 0; j >>= 1) {
            int ixj = t ^ j;
            if (ixj > t) {
                float A = s[t], Bv = s[ixj];
                bool desc = ((t & k) == 0);
                bool sw = desc ? (A < Bv) : (A > Bv);
                if (sw) { s[t] = Bv; s[ixj] = A; }
            }
            __syncthreads();
        }
    }
    float cmax = s[0];
    float t0 = s[127], t1 = s[169], t2 = s[191], t3 = s[203];  // k-1 for k = 128,170,192,204
    float e = __expf(c - cmax);
    float w0 = (c >= t0) ? e : 0.f;
    float w1 = (c >= t1) ? e : 0.f;
    float w2 = (c >= t2) ? e : 0.f;
    float w3 = (c >= t3) ? e : 0.f;
    float v0 = w0, v1 = w1, v2 = w2, v3 = w3;
    #pragma unroll
    for (int m = 1; m < 64; m <<= 1) {
        v0 += __shfl_xor(v0, m); v1 += __shfl_xor(v1, m);
        v2 += __shfl_xor(v2, m); v3 += __shfl_xor(v3, m);
    }
    int lane = t & 63, wv = t >> 6;
    if (lane == 0) { wred[wv][0] = v0; wred[wv][1] = v1; wred[wv][2] = v2; wred[wv][3] = v3; }
    __syncthreads();
    float S0 = wred[0][0] + wred[1][0] + wred[2][0] + wred[3][0];
    float S1 = wred[0][1] + wred[1][1] + wred[2][1] + wred[3][1];
    float S2 = wred[0][2] + wred[1][2] + wred[2][2] + wred[3][2];
    float S3 = wred[0][3] + wred[1][3] + wred[2][3] + wred[3][3];
    float Mv = a1p[0] * (w0 / S0) + a2p[0] * (w1 / S1) + a3p[0] * (w2 / S2) + a4p[0] * (w3 / S3);
    Mo[(b * Dd + d) * Dd + t] = Mv;
}

// K6: W2[b][o][e] = sum_c Wr[o][c] * M[b][c][e], stored bf16 row-major [o][e] (MFMA A-ready).
__global__ __launch_bounds__(256) void mg_k6_w2(const float* __restrict__ Wr, float* __restrict__ ws)
{
    const float* Mo = ws + OFF_M;
    ushort* W2B = (ushort*)(ws + OFF_W2T);
    __shared__ float Mt[32][128];
    __shared__ float WrT[32][36];
    int t = threadIdx.x;
    int b = blockIdx.x >> 5, ob = (blockIdx.x >> 1) & 15, eh = blockIdx.x & 1;
    int o0 = ob * 32, e0 = eh * 128;
    int ol4 = t & 7, el = t >> 3;
    float acc[4][4];
    #pragma unroll
    for (int i = 0; i < 4; ++i)
        #pragma unroll
        for (int j = 0; j < 4; ++j) acc[i][j] = 0.f;

    for (int ch = 0; ch < 8; ++ch) {
        int c0 = ch * 32;
        __syncthreads();
        #pragma unroll
        for (int k = 0; k < 4; ++k) {
            int fi = t + k * 256;
            int row = fi >> 5, c4 = fi & 31;
            float4 mv = ((const float4*)Mo)[(b * Dd + c0 + row) * 64 + (e0 >> 2) + c4];
            *(float4*)&Mt[row][c4 * 4] = mv;
        }
        {
            int ol = t >> 3, c4 = t & 7;
            float4 wv = ((const float4*)Wr)[(o0 + ol) * 64 + (c0 >> 2) + c4];
            WrT[c4 * 4 + 0][ol] = wv.x;
            WrT[c4 * 4 + 1][ol] = wv.y;
            WrT[c4 * 4 + 2][ol] = wv.z;
            WrT[c4 * 4 + 3][ol] = wv.w;
        }
        __syncthreads();
        #pragma unroll
        for (int cc = 0; cc < 32; ++cc) {
            float4 w4 = *(const float4*)&WrT[cc][ol4 * 4];
            float4 m4 = *(const float4*)&Mt[cc][el * 4];
            float wv[4] = {w4.x, w4.y, w4.z, w4.w};
            float mv[4] = {m4.x, m4.y, m4.z, m4.w};
            #pragma unroll
            for (int i = 0; i < 4; ++i)
                #pragma unroll
                for (int j = 0; j < 4; ++j)
                    acc[i][j] = fmaf(wv[i], mv[j], acc[i][j]);
        }
    }
    #pragma unroll
    for (int i = 0; i < 4; ++i) {
        int o = o0 + ol4 * 4 + i;
        ushort4 u;
        u.x = f2bf(acc[i][0]); u.y = f2bf(acc[i][1]);
        u.z = f2bf(acc[i][2]); u.w = f2bf(acc[i][3]);
        *(ushort4*)&W2B[((size_t)b * Oo + o) * Dd + e0 + el * 4] = u;
    }
}

// K7 v2 (MFMA, deep tile): out[b][o][n0+n] = LN_o( sum_e W2[o][e]*q[e][n] + br[o] )*g2 + b2
// grid: b(8) x nt(144); block 256 thr (4 waves), tile 512o x 64n; wave = 128o x 64n.
// af (W2 frags) batched 8-wide + double-buffered across K-steps for prefetch distance.
__global__ __launch_bounds__(256, 2) void mg_k7_final(const float* __restrict__ x2,
        const float* __restrict__ g1, const float* __restrict__ b1,
        const float* __restrict__ br, const float* __restrict__ g2, const float* __restrict__ b2,
        const float* __restrict__ ws, float* __restrict__ out)
{
    __shared__ ushort qsT[64 * 256];          // q^T tile [n][e] bf16, 16B-granule XOR swizzle
    __shared__ float stat[4][4][16][2];       // [wave][nt][colA][S,Q]
    __shared__ float musig[64][2];

    const float* mu2    = ws + OFF_MU2;
    const float* rstd2  = ws + OFF_RSTD2;
    const float* rowinv = ws + OFF_ROWINV;
    const ushort* W2B   = (const ushort*)(ws + OFF_W2T);

    int t = threadIdx.x;
    int b = blockIdx.x / 144, nt0 = blockIdx.x % 144;
    int n0 = nt0 * 64;

    // stage q^T: 64 rows x 256 e; thread t: row = t>>2, granules (t&3)*8 .. +7
    {
        int row = t >> 2, gb = (t & 3) * 8;
        int ni = b * Nn + n0 + row;
        float m = mu2[ni], r = rstd2[ni], ri = rowinv[ni];
        #pragma unroll
        for (int j = 0; j < 8; ++j) {
            int g = gb + j;
            int e = g * 8;
            const float4* xp = (const float4*)x2 + (size_t)ni * 64 + g * 2;
            float4 xa = xp[0], xb = xp[1];
            float4 ga = ((const float4*)g1)[g * 2], gb4 = ((const float4*)g1)[g * 2 + 1];
            float4 ba = ((const float4*)b1)[g * 2], bb4 = ((const float4*)b1)[g * 2 + 1];
            float v[8]  = {xa.x, xa.y, xa.z, xa.w, xb.x, xb.y, xb.z, xb.w};
            float gv[8] = {ga.x, ga.y, ga.z, ga.w, gb4.x, gb4.y, gb4.z, gb4.w};
            float bv[8] = {ba.x, ba.y, ba.z, ba.w, bb4.x, bb4.y, bb4.z, bb4.w};
            ushort8 u;
            #pragma unroll
            for (int q = 0; q < 8; ++q)
                u[q] = f2bf(__expf((v[q] - m) * r * gv[q] + bv[q]) * ri);
            (void)e;
            *(ushort8*)&qsT[row * 256 + ((g ^ (row & 7)) << 3)] = u;
        }
    }
    __syncthreads();

    int lw = t & 63, wave = t >> 6;
    int colA = lw & 15, kgrp = lw >> 4;

    f32x4 acc[8][4];
    #pragma unroll
    for (int ot = 0; ot < 8; ++ot)
        #pragma unroll
        for (int nt = 0; nt < 4; ++nt)
            acc[ot][nt] = (f32x4){0.f, 0.f, 0.f, 0.f};

    // A: W2B[b][o = wave*128 + ot*16 + colA][e = ks*32 + kgrp*8 + j]
    const ushort* abase = W2B + ((size_t)b * Oo + wave * 128 + colA) * Dd + kgrp * 8;

#define LOADAF(dst, ksv)                                                        \
    {                                                                           \
        _Pragma("unroll")                                                       \
        for (int ot = 0; ot < 8; ++ot)                                          \
            dst[ot] = *(const short8*)&abase[(size_t)ot * 16 * Dd + (ksv) * 32];\
    }

#define MFMASTEP(afv, ksv)                                                      \
    {                                                                           \
        short8 bf[4];                                                           \
        int gsl = (((ksv) * 4 + kgrp) ^ (colA & 7)) << 3;                       \
        _Pragma("unroll")                                                       \
        for (int nt = 0; nt < 4; ++nt)                                          \
            bf[nt] = *(const short8*)&qsT[(nt * 16 + colA) * 256 + gsl];        \
        _Pragma("unroll")                                                       \
        for (int ot = 0; ot < 8; ++ot)                                          \
            _Pragma("unroll")                                                   \
            for (int nt = 0; nt < 4; ++nt)                                      \
                acc[ot][nt] = __builtin_amdgcn_mfma_f32_16x16x32_bf16(          \
                    afv[ot], bf[nt], acc[ot][nt], 0, 0, 0);                     \
    }

    short8 afA[8], afB[8];
    LOADAF(afA, 0);
    #pragma unroll
    for (int kp = 0; kp < 4; ++kp) {
        LOADAF(afB, 2 * kp + 1);
        MFMASTEP(afA, 2 * kp);
        if (kp < 3) LOADAF(afA, 2 * kp + 2);
        MFMASTEP(afB, 2 * kp + 1);
    }
#undef LOADAF
#undef MFMASTEP

    // epilogue: +br, LN over 512 o per n-column, store transposed
    float ps[4] = {0.f, 0.f, 0.f, 0.f}, pq[4] = {0.f, 0.f, 0.f, 0.f};
    #pragma unroll
    for (int ot = 0; ot < 8; ++ot) {
        #pragma unroll
        for (int r = 0; r < 4; ++r) {
            int o = wave * 128 + ot * 16 + kgrp * 4 + r;
            float bb = br[o];
            #pragma unroll
            for (int nt = 0; nt < 4; ++nt) {
                float v = acc[ot][nt][r] + bb;
                acc[ot][nt][r] = v;
                ps[nt] += v; pq[nt] += v * v;
            }
        }
    }
    #pragma unroll
    for (int m = 16; m <= 32; m <<= 1) {
        #pragma unroll
        for (int nt = 0; nt < 4; ++nt) {
            ps[nt] += __shfl_xor(ps[nt], m);
            pq[nt] += __shfl_xor(pq[nt], m);
        }
    }
    if (lw < 16) {
        #pragma unroll
        for (int nt = 0; nt < 4; ++nt) {
            stat[wave][nt][lw][0] = ps[nt];
            stat[wave][nt][lw][1] = pq[nt];
        }
    }
    __syncthreads();
    if (t < 64) {
        int ntl = t >> 4, col = t & 15;
        float S = 0.f, Q = 0.f;
        #pragma unroll
        for (int w2 = 0; w2 < 4; ++w2) { S += stat[w2][ntl][col][0]; Q += stat[w2][ntl][col][1]; }
        float mu = S * (1.f / Oo);
        float var = Q * (1.f / Oo) - mu * mu;
        musig[t][0] = mu;
        musig[t][1] = rsqrtf(var + EPSc);
    }
    __syncthreads();

    float mn[4], rs[4];
    #pragma unroll
    for (int nt = 0; nt < 4; ++nt) {
        mn[nt] = musig[nt * 16 + colA][0];
        rs[nt] = musig[nt * 16 + colA][1];
    }
    #pragma unroll
    for (int ot = 0; ot < 8; ++ot) {
        #pragma unroll
        for (int r = 0; r < 4; ++r) {
            int o = wave * 128 + ot * 16 + kgrp * 4 + r;
            float gg = g2[o], bb2 = b2[o];
            size_t ob = ((size_t)b * Oo + o) * Nn + n0;
            #pragma unroll
            for (int nt = 0; nt < 4; ++nt)
                out[ob + nt * 16 + colA] = (acc[ot][nt][r] - mn[nt]) * rs[nt] * gg + bb2;
        }
    }
}

extern "C" void kernel_launch(void* const* d_in, const int* in_sizes, int n_in,
                              void* d_out, int out_size, void* d_ws, size_t ws_size,
                              hipStream_t stream)
{
    (void)in_sizes; (void)n_in; (void)out_size;
    const float* x1 = (const float*)d_in[0];
    const float* x2 = (const float*)d_in[1];
    const float* g1 = (const float*)d_in[2];
    const float* b1 = (const float*)d_in[3];
    const float* Wr = (const float*)d_in[4];
    const float* br = (const float*)d_in[5];
    const float* g2 = (const float*)d_in[6];
    const float* b2 = (const float*)d_in[7];
    const float* a1 = (const float*)d_in[8];
    const float* a2 = (const float*)d_in[9];
    const float* a3 = (const float*)d_in[10];
    const float* a4 = (const float*)d_in[11];
    float* ws = (float*)d_ws;
    float* out = (float*)d_out;

    // adaptive split-K: nks must divide 144 (so krange % 64 == 0) and partials must fit ws
    const int cand[6] = {24, 16, 12, 8, 4, 2};
    int nks = 2;
    for (int ci = 0; ci < 6; ++ci) {
        if ((2467840ull + (size_t)cand[ci] * 524288ull) * 4ull <= ws_size) { nks = cand[ci]; break; }
    }

    hipLaunchKernelGGL(mg_k0_zero, dim3(2), dim3(256), 0, stream, ws + OFF_COLSUM, 512);
    hipLaunchKernelGGL(mg_k1_stats, dim3(1152), dim3(256), 0, stream, x1, x2, g1, b1, ws);
    hipLaunchKernelGGL(mg_k3_ctx, dim3(Bc * nks), dim3(512), 0, stream, x1, x2, g1, b1, ws, nks);
    hipLaunchKernelGGL(mg_k5_mask, dim3(2048), dim3(256), 0, stream, a1, a2, a3, a4, ws, nks);
    hipLaunchKernelGGL(mg_k6_w2, dim3(256), dim3(256), 0, stream, Wr, ws);
    hipLaunchKernelGGL(mg_k7_final, dim3(1152), dim3(256), 0, stream, x2, g1, b1, br, g2, b2, ws, out);
}

// Round 7
// 200.906 us; speedup vs baseline: 4.3884x; 1.0791x over previous
//
#include <hip/hip_runtime.h>
#include <hip/hip_bf16.h>

#define Bc 8
#define Nn 9216
#define Dd 256
#define Oo 512
#define EPSc 1e-5f

// workspace float offsets
#define OFF_MU1    0
#define OFF_RSTD1  73728
#define OFF_MU2    147456
#define OFF_RSTD2  221184
#define OFF_ROWINV 294912
#define OFF_COLSUM 368640
#define OFF_M      894976
#define OFF_W2T    1419264   // W2 bf16 [b][ks][o][32e] = 2 MB (524288 float slots)
#define OFF_CTXP   2467840   // nks * 524288 floats of ctx partials (adaptive)

typedef __attribute__((ext_vector_type(4))) float f32x4;
typedef __attribute__((ext_vector_type(8))) short short8;
typedef __attribute__((ext_vector_type(8))) unsigned short ushort8;

static __device__ __forceinline__ unsigned short f2bf(float f) {
    __hip_bfloat16 h = __float2bfloat16(f);
    union { __hip_bfloat16 hh; unsigned short uu; } cv; cv.hh = h;
    return cv.uu;
}

// granule swizzle for channel-major bf16 tiles [ch][64n]: write conflict-free, read ~2-way
#define SWZ(ch) (((((ch) >> 2) & 7)) ^ ((((ch) & 3)) << 1))

__global__ __launch_bounds__(256) void mg_k0_zero(float* __restrict__ p, int n4) {
    int i = blockIdx.x * 256 + threadIdx.x;
    if (i < n4) ((float4*)p)[i] = make_float4(0.f, 0.f, 0.f, 0.f);
}

// K1: one pass over x1,x2. Per row: LN stats for both; query row-sumexp; col-sumexp partials -> atomics.
__global__ __launch_bounds__(256) void mg_k1_stats(const float* __restrict__ x1, const float* __restrict__ x2,
                                                   const float* __restrict__ g1, const float* __restrict__ b1,
                                                   float* __restrict__ ws)
{
    float* mu1    = ws + OFF_MU1;
    float* rstd1  = ws + OFF_RSTD1;
    float* mu2    = ws + OFF_MU2;
    float* rstd2  = ws + OFF_RSTD2;
    float* rowinv = ws + OFF_ROWINV;
    float* colsum = ws + OFF_COLSUM;

    int t = threadIdx.x, lane = t & 63, w = t >> 6;
    int b = blockIdx.x / 144, rb = blockIdx.x % 144;
    int nbase = rb * 64;

    float4 g1v = ((const float4*)g1)[lane];
    float4 b1v = ((const float4*)b1)[lane];
    float cs0 = 0.f, cs1 = 0.f, cs2 = 0.f, cs3 = 0.f;
    __shared__ float csL[4][256];

    for (int i = 0; i < 16; ++i) {
        int n = nbase + i * 4 + w;
        int base = (b * Nn + n) * 64 + lane;
        float4 xa = ((const float4*)x1)[base];
        float4 xb = ((const float4*)x2)[base];
        float s1 = xa.x + xa.y + xa.z + xa.w;
        float q1 = xa.x*xa.x + xa.y*xa.y + xa.z*xa.z + xa.w*xa.w;
        float s2 = xb.x + xb.y + xb.z + xb.w;
        float q2 = xb.x*xb.x + xb.y*xb.y + xb.z*xb.z + xb.w*xb.w;
        #pragma unroll
        for (int m = 1; m < 64; m <<= 1) {
            s1 += __shfl_xor(s1, m); q1 += __shfl_xor(q1, m);
            s2 += __shfl_xor(s2, m); q2 += __shfl_xor(q2, m);
        }
        float m1 = s1 * (1.f / Dd), m2 = s2 * (1.f / Dd);
        float r1 = rsqrtf(q1 * (1.f / Dd) - m1 * m1 + EPSc);
        float r2 = rsqrtf(q2 * (1.f / Dd) - m2 * m2 + EPSc);
        int ni = b * Nn + n;
        if (lane == 0) { mu1[ni] = m1; rstd1[ni] = r1; mu2[ni] = m2; rstd2[ni] = r2; }
        float e0 = __expf((xb.x - m2) * r2 * g1v.x + b1v.x);
        float e1 = __expf((xb.y - m2) * r2 * g1v.y + b1v.y);
        float e2 = __expf((xb.z - m2) * r2 * g1v.z + b1v.z);
        float e3 = __expf((xb.w - m2) * r2 * g1v.w + b1v.w);
        float rs = e0 + e1 + e2 + e3;
        #pragma unroll
        for (int m = 1; m < 64; m <<= 1) rs += __shfl_xor(rs, m);
        if (lane == 0) rowinv[ni] = 1.f / rs;
        cs0 += e0; cs1 += e1; cs2 += e2; cs3 += e3;
    }
    csL[w][lane * 4 + 0] = cs0;
    csL[w][lane * 4 + 1] = cs1;
    csL[w][lane * 4 + 2] = cs2;
    csL[w][lane * 4 + 3] = cs3;
    __syncthreads();
    float tot = csL[0][t] + csL[1][t] + csL[2][t] + csL[3][t];
    atomicAdd(&colsum[b * Dd + t], tot);
}

// K3 (MFMA): ctx_partial[p][b][d][e] = sum_{n in slice p} exp(n2[n][d]) * n1[n][e]
__global__ __launch_bounds__(512, 2) void mg_k3_ctx(const float* __restrict__ x1, const float* __restrict__ x2,
                                                    const float* __restrict__ g1, const float* __restrict__ b1,
                                                    float* __restrict__ ws, int nks)
{
    __shared__ ushort PA[256 * 64];   // exp(n2): [d][n]
    __shared__ ushort PB[256 * 64];   // n1:      [e][n]
    const float* mu1   = ws + OFF_MU1;
    const float* rstd1 = ws + OFF_RSTD1;
    const float* mu2   = ws + OFF_MU2;
    const float* rstd2 = ws + OFF_RSTD2;
    float* ctxp = ws + OFF_CTXP;

    int t = threadIdx.x;
    int ks_i = blockIdx.x % nks;
    int b = blockIdx.x / nks;
    int krange = Nn / nks;
    int ntiles = krange >> 6;
    int n_base = ks_i * krange;

    int o  = t >> 6;
    int c4 = t & 63;

    f32x4 g1v = ((const f32x4*)g1)[c4];
    f32x4 b1v = ((const f32x4*)b1)[c4];

    int lane = t & 63, wave = t >> 6;
    int wd = wave & 3, we = wave >> 2;
    int l15 = lane & 15, kgrp = lane >> 4;

    f32x4 acc[4][8];
    #pragma unroll
    for (int dt = 0; dt < 4; ++dt)
        #pragma unroll
        for (int et = 0; et < 8; ++et) acc[dt][et] = (f32x4){0.f, 0.f, 0.f, 0.f};

    for (int st = 0; st < ntiles; ++st) {
        int rowb = b * Nn + n_base + st * 64 + o * 8;
        __syncthreads();
        {
            f32x4 mv0 = *(const f32x4*)(mu1 + rowb),   mv1 = *(const f32x4*)(mu1 + rowb + 4);
            f32x4 rv0 = *(const f32x4*)(rstd1 + rowb), rv1 = *(const f32x4*)(rstd1 + rowb + 4);
            float mva[8] = {mv0[0], mv0[1], mv0[2], mv0[3], mv1[0], mv1[1], mv1[2], mv1[3]};
            float rva[8] = {rv0[0], rv0[1], rv0[2], rv0[3], rv1[0], rv1[1], rv1[2], rv1[3]};
            f32x4 xv[8];
            #pragma unroll
            for (int rr = 0; rr < 8; ++rr)
                xv[rr] = ((const f32x4*)x1)[(size_t)(rowb + rr) * 64 + c4];
            #pragma unroll
            for (int i = 0; i < 4; ++i) {
                int ch = c4 * 4 + i;
                ushort8 u;
                #pragma unroll
                for (int rr = 0; rr < 8; ++rr)
                    u[rr] = f2bf((xv[rr][i] - mva[rr]) * rva[rr] * g1v[i] + b1v[i]);
                *(ushort8*)&PB[ch * 64 + ((o + SWZ(ch)) & 7) * 8] = u;
            }
        }
        {
            f32x4 mv0 = *(const f32x4*)(mu2 + rowb),   mv1 = *(const f32x4*)(mu2 + rowb + 4);
            f32x4 rv0 = *(const f32x4*)(rstd2 + rowb), rv1 = *(const f32x4*)(rstd2 + rowb + 4);
            float mva[8] = {mv0[0], mv0[1], mv0[2], mv0[3], mv1[0], mv1[1], mv1[2], mv1[3]};
            float rva[8] = {rv0[0], rv0[1], rv0[2], rv0[3], rv1[0], rv1[1], rv1[2], rv1[3]};
            f32x4 xv[8];
            #pragma unroll
            for (int rr = 0; rr < 8; ++rr)
                xv[rr] = ((const f32x4*)x2)[(size_t)(rowb + rr) * 64 + c4];
            #pragma unroll
            for (int i = 0; i < 4; ++i) {
                int ch = c4 * 4 + i;
                ushort8 u;
                #pragma unroll
                for (int rr = 0; rr < 8; ++rr)
                    u[rr] = f2bf(__expf((xv[rr][i] - mva[rr]) * rva[rr] * g1v[i] + b1v[i]));
                *(ushort8*)&PA[ch * 64 + ((o + SWZ(ch)) & 7) * 8] = u;
            }
        }
        __syncthreads();

        #pragma unroll
        for (int kk = 0; kk < 2; ++kk) {
            short8 af[4], bf[8];
            #pragma unroll
            for (int dt = 0; dt < 4; ++dt) {
                int ch = wd * 64 + dt * 16 + l15;
                af[dt] = *(const short8*)&PA[ch * 64 + (((kk << 2) + kgrp + SWZ(ch)) & 7) * 8];
            }
            #pragma unroll
            for (int et = 0; et < 8; ++et) {
                int ch = we * 128 + et * 16 + l15;
                bf[et] = *(const short8*)&PB[ch * 64 + (((kk << 2) + kgrp + SWZ(ch)) & 7) * 8];
            }
            #pragma unroll
            for (int dt = 0; dt < 4; ++dt)
                #pragma unroll
                for (int et = 0; et < 8; ++et)
                    acc[dt][et] = __builtin_amdgcn_mfma_f32_16x16x32_bf16(af[dt], bf[et], acc[dt][et], 0, 0, 0);
        }
    }

    size_t obase = ((size_t)ks_i * Bc + b) * (Dd * Dd);
    #pragma unroll
    for (int dt = 0; dt < 4; ++dt) {
        #pragma unroll
        for (int r = 0; r < 4; ++r) {
            int d = wd * 64 + dt * 16 + kgrp * 4 + r;
            float* rowp = ctxp + obase + (size_t)d * Dd + we * 128 + l15;
            #pragma unroll
            for (int et = 0; et < 8; ++et)
                rowp[et * 16] = acc[dt][et][r];
        }
    }
}

// K5: reduce ctx partials, scale by 1/colsum, bitonic sort (desc), 4 top-k thresholds,
// combined masked softmax M = sum_i a_i * softmax_masked_i.  grid = B*D rows.
__global__ __launch_bounds__(256) void mg_k5_mask(const float* __restrict__ a1p, const float* __restrict__ a2p,
                                                  const float* __restrict__ a3p, const float* __restrict__ a4p,
                                                  float* __restrict__ ws, int nks)
{
    const float* ctxp   = ws + OFF_CTXP;
    const float* colsum = ws + OFF_COLSUM;
    float* Mo = ws + OFF_M;
    int t = threadIdx.x;
    int b = blockIdx.x >> 8, d = blockIdx.x & 255;
    __shared__ float s[256];
    __shared__ float wred[4][4];

    float c = 0.f;
    for (int p = 0; p < nks; ++p)
        c += ctxp[((size_t)p * Bc + b) * (Dd * Dd) + (size_t)d * Dd + t];
    float inv = 1.f / colsum[b * Dd + d];
    c *= inv;
    s[t] = c;
    __syncthreads();
    for (int k = 2; k <= 256; k <<= 1) {
        for (int j = k >> 1; j > 0; j >>= 1) {
            int ixj = t ^ j;
            if (ixj > t) {
                float A = s[t], Bv = s[ixj];
                bool desc = ((t & k) == 0);
                bool sw = desc ? (A < Bv) : (A > Bv);
                if (sw) { s[t] = Bv; s[ixj] = A; }
            }
            __syncthreads();
        }
    }
    float cmax = s[0];
    float t0 = s[127], t1 = s[169], t2 = s[191], t3 = s[203];  // k-1 for k = 128,170,192,204
    float e = __expf(c - cmax);
    float w0 = (c >= t0) ? e : 0.f;
    float w1 = (c >= t1) ? e : 0.f;
    float w2 = (c >= t2) ? e : 0.f;
    float w3 = (c >= t3) ? e : 0.f;
    float v0 = w0, v1 = w1, v2 = w2, v3 = w3;
    #pragma unroll
    for (int m = 1; m < 64; m <<= 1) {
        v0 += __shfl_xor(v0, m); v1 += __shfl_xor(v1, m);
        v2 += __shfl_xor(v2, m); v3 += __shfl_xor(v3, m);
    }
    int lane = t & 63, wv = t >> 6;
    if (lane == 0) { wred[wv][0] = v0; wred[wv][1] = v1; wred[wv][2] = v2; wred[wv][3] = v3; }
    __syncthreads();
    float S0 = wred[0][0] + wred[1][0] + wred[2][0] + wred[3][0];
    float S1 = wred[0][1] + wred[1][1] + wred[2][1] + wred[3][1];
    float S2 = wred[0][2] + wred[1][2] + wred[2][2] + wred[3][2];
    float S3 = wred[0][3] + wred[1][3] + wred[2][3] + wred[3][3];
    float Mv = a1p[0] * (w0 / S0) + a2p[0] * (w1 / S1) + a3p[0] * (w2 / S2) + a4p[0] * (w3 / S3);
    Mo[(b * Dd + d) * Dd + t] = Mv;
}

// K6: W2[b][ks][o][32e] = sum_c Wr[o][c] * M[b][c][e] (bf16, K-step-major for K7 coalescing)
__global__ __launch_bounds__(256) void mg_k6_w2(const float* __restrict__ Wr, float* __restrict__ ws)
{
    const float* Mo = ws + OFF_M;
    ushort* W2B = (ushort*)(ws + OFF_W2T);
    __shared__ float Mt[32][128];
    __shared__ float WrT[32][36];
    int t = threadIdx.x;
    int b = blockIdx.x >> 5, ob = (blockIdx.x >> 1) & 15, eh = blockIdx.x & 1;
    int o0 = ob * 32, e0 = eh * 128;
    int ol4 = t & 7, el = t >> 3;
    float acc[4][4];
    #pragma unroll
    for (int i = 0; i < 4; ++i)
        #pragma unroll
        for (int j = 0; j < 4; ++j) acc[i][j] = 0.f;

    for (int ch = 0; ch < 8; ++ch) {
        int c0 = ch * 32;
        __syncthreads();
        #pragma unroll
        for (int k = 0; k < 4; ++k) {
            int fi = t + k * 256;
            int row = fi >> 5, c4 = fi & 31;
            float4 mv = ((const float4*)Mo)[(b * Dd + c0 + row) * 64 + (e0 >> 2) + c4];
            *(float4*)&Mt[row][c4 * 4] = mv;
        }
        {
            int ol = t >> 3, c4 = t & 7;
            float4 wv = ((const float4*)Wr)[(o0 + ol) * 64 + (c0 >> 2) + c4];
            WrT[c4 * 4 + 0][ol] = wv.x;
            WrT[c4 * 4 + 1][ol] = wv.y;
            WrT[c4 * 4 + 2][ol] = wv.z;
            WrT[c4 * 4 + 3][ol] = wv.w;
        }
        __syncthreads();
        #pragma unroll
        for (int cc = 0; cc < 32; ++cc) {
            float4 w4 = *(const float4*)&WrT[cc][ol4 * 4];
            float4 m4 = *(const float4*)&Mt[cc][el * 4];
            float wv[4] = {w4.x, w4.y, w4.z, w4.w};
            float mv[4] = {m4.x, m4.y, m4.z, m4.w};
            #pragma unroll
            for (int i = 0; i < 4; ++i)
                #pragma unroll
                for (int j = 0; j < 4; ++j)
                    acc[i][j] = fmaf(wv[i], mv[j], acc[i][j]);
        }
    }
    {
        int ee = e0 + el * 4;
        int ks = ee >> 5, eloc = ee & 31;
        #pragma unroll
        for (int i = 0; i < 4; ++i) {
            int o = o0 + ol4 * 4 + i;
            ushort4 u;
            u.x = f2bf(acc[i][0]); u.y = f2bf(acc[i][1]);
            u.z = f2bf(acc[i][2]); u.w = f2bf(acc[i][3]);
            *(ushort4*)&W2B[(((size_t)b * 8 + ks) * Oo + o) * 32 + eloc] = u;
        }
    }
}

// K7 v3 (MFMA, occupancy-first): out[b][o][n0+n] = LN_o( sum_e W2[o][e]*q[e][n] + br[o] )*g2+b2
// grid: b(8) x nt(288); block 512 thr (8 waves), tile 512o x 32n; wave = 64o x 32n.
// W2 is K-step-major [b][ks][o][32e]: af loads fully coalesced (1 KB contiguous per instr).
__global__ __launch_bounds__(512) void mg_k7_final(const float* __restrict__ x2,
        const float* __restrict__ g1, const float* __restrict__ b1,
        const float* __restrict__ br, const float* __restrict__ g2, const float* __restrict__ b2,
        const float* __restrict__ ws, float* __restrict__ out)
{
    __shared__ ushort qsT[32 * 256];          // q^T tile [n][e] bf16, 16B-granule XOR swizzle
    __shared__ float stat[8][2][16][2];       // [wave][nt][colA][S,Q]
    __shared__ float musig[32][2];

    const float* mu2    = ws + OFF_MU2;
    const float* rstd2  = ws + OFF_RSTD2;
    const float* rowinv = ws + OFF_ROWINV;
    const ushort* W2B   = (const ushort*)(ws + OFF_W2T);

    int t = threadIdx.x;
    int b = blockIdx.x / 288, nt0 = blockIdx.x % 288;
    int n0 = nt0 * 32;

    // stage q^T: 32 rows x 256 e; thread: row = t>>4, granules (t&15)*2 .. +1
    {
        int row = t >> 4, gb = (t & 15) * 2;
        int ni = b * Nn + n0 + row;
        float m = mu2[ni], r = rstd2[ni], ri = rowinv[ni];
        #pragma unroll
        for (int jj = 0; jj < 2; ++jj) {
            int g = gb + jj;
            const float4* xp = (const float4*)x2 + (size_t)ni * 64 + g * 2;
            float4 xa = xp[0], xb = xp[1];
            float4 ga = ((const float4*)g1)[g * 2], gc = ((const float4*)g1)[g * 2 + 1];
            float4 ba = ((const float4*)b1)[g * 2], bc = ((const float4*)b1)[g * 2 + 1];
            float v[8]  = {xa.x, xa.y, xa.z, xa.w, xb.x, xb.y, xb.z, xb.w};
            float gv[8] = {ga.x, ga.y, ga.z, ga.w, gc.x, gc.y, gc.z, gc.w};
            float bv[8] = {ba.x, ba.y, ba.z, ba.w, bc.x, bc.y, bc.z, bc.w};
            ushort8 u;
            #pragma unroll
            for (int q = 0; q < 8; ++q)
                u[q] = f2bf(__expf((v[q] - m) * r * gv[q] + bv[q]) * ri);
            *(ushort8*)&qsT[row * 256 + ((g ^ (row & 7)) << 3)] = u;
        }
    }
    __syncthreads();

    int lw = t & 63, wave = t >> 6;
    int colA = lw & 15, kgrp = lw >> 4;

    f32x4 acc[4][2];
    #pragma unroll
    for (int ot = 0; ot < 4; ++ot) {
        acc[ot][0] = (f32x4){0.f, 0.f, 0.f, 0.f};
        acc[ot][1] = (f32x4){0.f, 0.f, 0.f, 0.f};
    }

    // af lane address: W2B[((b*8 + ks)*Oo + wave*64 + ot*16 + colA)*32 + kgrp*8 ..]
    const ushort* abase = W2B + ((size_t)b * 8 * Oo + wave * 64 + colA) * 32 + kgrp * 8;

#define LOADAF(dst, ksv)                                                         \
    {                                                                            \
        _Pragma("unroll")                                                        \
        for (int ot = 0; ot < 4; ++ot)                                           \
            dst[ot] = *(const short8*)&abase[((size_t)(ksv) * Oo + ot * 16) * 32];\
    }

#define MFMASTEP(afv, ksv)                                                       \
    {                                                                            \
        int gsl = (((ksv) * 4 + kgrp) ^ (colA & 7)) << 3;                        \
        short8 bf0 = *(const short8*)&qsT[colA * 256 + gsl];                     \
        short8 bf1 = *(const short8*)&qsT[(16 + colA) * 256 + gsl];              \
        _Pragma("unroll")                                                        \
        for (int ot = 0; ot < 4; ++ot) {                                         \
            acc[ot][0] = __builtin_amdgcn_mfma_f32_16x16x32_bf16(                \
                afv[ot], bf0, acc[ot][0], 0, 0, 0);                              \
            acc[ot][1] = __builtin_amdgcn_mfma_f32_16x16x32_bf16(                \
                afv[ot], bf1, acc[ot][1], 0, 0, 0);                              \
        }                                                                        \
    }

    short8 afA[4], afB[4];
    LOADAF(afA, 0);
    #pragma unroll
    for (int kp = 0; kp < 4; ++kp) {
        LOADAF(afB, 2 * kp + 1);
        MFMASTEP(afA, 2 * kp);
        if (kp < 3) LOADAF(afA, 2 * kp + 2);
        MFMASTEP(afB, 2 * kp + 1);
    }
#undef LOADAF
#undef MFMASTEP

    // epilogue: +br, LN over 512 o per n-column, store transposed
    float ps[2] = {0.f, 0.f}, pq[2] = {0.f, 0.f};
    #pragma unroll
    for (int ot = 0; ot < 4; ++ot) {
        #pragma unroll
        for (int r = 0; r < 4; ++r) {
            int o = wave * 64 + ot * 16 + kgrp * 4 + r;
            float bb = br[o];
            float v0 = acc[ot][0][r] + bb;
            float v1 = acc[ot][1][r] + bb;
            acc[ot][0][r] = v0; acc[ot][1][r] = v1;
            ps[0] += v0; pq[0] += v0 * v0;
            ps[1] += v1; pq[1] += v1 * v1;
        }
    }
    #pragma unroll
    for (int m = 16; m <= 32; m <<= 1) {
        ps[0] += __shfl_xor(ps[0], m); pq[0] += __shfl_xor(pq[0], m);
        ps[1] += __shfl_xor(ps[1], m); pq[1] += __shfl_xor(pq[1], m);
    }
    if (lw < 16) {
        stat[wave][0][lw][0] = ps[0]; stat[wave][0][lw][1] = pq[0];
        stat[wave][1][lw][0] = ps[1]; stat[wave][1][lw][1] = pq[1];
    }
    __syncthreads();
    if (t < 32) {
        int ntl = t >> 4, col = t & 15;
        float S = 0.f, Q = 0.f;
        #pragma unroll
        for (int w2 = 0; w2 < 8; ++w2) { S += stat[w2][ntl][col][0]; Q += stat[w2][ntl][col][1]; }
        float mu = S * (1.f / Oo);
        float var = Q * (1.f / Oo) - mu * mu;
        musig[t][0] = mu;
        musig[t][1] = rsqrtf(var + EPSc);
    }
    __syncthreads();

    float mn0 = musig[colA][0],      rs0 = musig[colA][1];
    float mn1 = musig[16 + colA][0], rs1 = musig[16 + colA][1];
    #pragma unroll
    for (int ot = 0; ot < 4; ++ot) {
        #pragma unroll
        for (int r = 0; r < 4; ++r) {
            int o = wave * 64 + ot * 16 + kgrp * 4 + r;
            float gg = g2[o], bb2 = b2[o];
            size_t ob = ((size_t)b * Oo + o) * Nn + n0;
            out[ob + colA]      = (acc[ot][0][r] - mn0) * rs0 * gg + bb2;
            out[ob + 16 + colA] = (acc[ot][1][r] - mn1) * rs1 * gg + bb2;
        }
    }
}

extern "C" void kernel_launch(void* const* d_in, const int* in_sizes, int n_in,
                              void* d_out, int out_size, void* d_ws, size_t ws_size,
                              hipStream_t stream)
{
    (void)in_sizes; (void)n_in; (void)out_size;
    const float* x1 = (const float*)d_in[0];
    const float* x2 = (const float*)d_in[1];
    const float* g1 = (const float*)d_in[2];
    const float* b1 = (const float*)d_in[3];
    const float* Wr = (const float*)d_in[4];
    const float* br = (const float*)d_in[5];
    const float* g2 = (const float*)d_in[6];
    const float* b2 = (const float*)d_in[7];
    const float* a1 = (const float*)d_in[8];
    const float* a2 = (const float*)d_in[9];
    const float* a3 = (const float*)d_in[10];
    const float* a4 = (const float*)d_in[11];
    float* ws = (float*)d_ws;
    float* out = (float*)d_out;

    // adaptive split-K: nks must divide 144 (so krange % 64 == 0) and partials must fit ws
    const int cand[6] = {24, 16, 12, 8, 4, 2};
    int nks = 2;
    for (int ci = 0; ci < 6; ++ci) {
        if ((2467840ull + (size_t)cand[ci] * 524288ull) * 4ull <= ws_size) { nks = cand[ci]; break; }
    }

    hipLaunchKernelGGL(mg_k0_zero, dim3(2), dim3(256), 0, stream, ws + OFF_COLSUM, 512);
    hipLaunchKernelGGL(mg_k1_stats, dim3(1152), dim3(256), 0, stream, x1, x2, g1, b1, ws);
    hipLaunchKernelGGL(mg_k3_ctx, dim3(Bc * nks), dim3(512), 0, stream, x1, x2, g1, b1, ws, nks);
    hipLaunchKernelGGL(mg_k5_mask, dim3(2048), dim3(256), 0, stream, a1, a2, a3, a4, ws, nks);
    hipLaunchKernelGGL(mg_k6_w2, dim3(256), dim3(256), 0, stream, Wr, ws);
    hipLaunchKernelGGL(mg_k7_final, dim3(2304), dim3(512), 0, stream, x2, g1, b1, br, g2, b2, ws, out);
}